// Round 1
// baseline (4109.090 us; speedup 1.0000x reference)
//
#include <hip/hip_runtime.h>
#include <cstdint>

#define NACT 512
#define NOBJ 3584
#define NTOT 4096
#define DCOLS 1028
#define NHID_ 257
#define WHLD 260
#define OFSZ 2048

// ---- workspace layout (float offsets; all 16B aligned) ----
static const size_t NX       = (size_t)NTOT * DCOLS;        // 4,210,688
static const size_t OFF_X0   = 0;
static const size_t OFF_G    = NX;
static const size_t OFF_T    = 2 * NX;
static const size_t OFF_WH   = 3 * NX;
static const size_t WH_SZ    = (size_t)4 * NTOT * WHLD;
static const size_t OFF_F1   = OFF_WH + WH_SZ;
static const size_t OFF_F2   = OFF_F1 + 4 * NTOT;
static const size_t OFF_RMAX = OFF_F2 + 4 * NTOT;
static const size_t OFF_RDEN = OFF_RMAX + 4 * NTOT;
static const size_t OFF_LOSSP= OFF_RDEN + 4 * NTOT;
static const size_t OFF_MASK = OFF_LOSSP + 512;             // u64 region (float off is even)

// ---------------- geo features ----------------
__global__ void k_geo(const float* __restrict__ ab, const float* __restrict__ ob,
                      float* __restrict__ X) {
    int n = blockIdx.x * blockDim.x + threadIdx.x;
    if (n >= NTOT) return;
    const float* b = (n < NACT) ? &ab[n * 4] : &ob[(n - NACT) * 4];
    float x0 = b[0], y0 = b[1], x1 = b[2], y1 = b[3];
    float* o = &X[(size_t)n * DCOLS + 1024];
    o[0] = y1 - y0;
    o[1] = x1 - x0;
    o[2] = (x1 - x0) * 0.5f + x0;
    o[3] = (y1 - y0) * 0.5f + y0;
}

// ---------------- mean-pool 196 -> 1 ----------------
__global__ __launch_bounds__(256) void k_meanpool(const float* __restrict__ af,
                                                  float* __restrict__ X) {
    int w = blockIdx.x * 4 + (threadIdx.x >> 6);   // wave id == (n*1024+c)
    int lane = threadIdx.x & 63;
    const float* src = af + (size_t)w * 196;
    float s = src[lane] + src[lane + 64] + src[lane + 128];
    if (lane < 4) s += src[192 + lane];
    #pragma unroll
    for (int off = 32; off; off >>= 1) s += __shfl_down(s, off);
    if (lane == 0) {
        int n = w >> 10, c = w & 1023;
        X[(size_t)n * DCOLS + c] = s * (1.0f / 196.0f);
    }
}

// ---------------- pack adjacency into bitmask ----------------
__global__ __launch_bounds__(256) void k_packmask(const int* __restrict__ adj,
                                                  unsigned long long* __restrict__ mb) {
    int w = blockIdx.x * 4 + (threadIdx.x >> 6);   // word id; covers row w/64, cols (w%64)*64..
    int lane = threadIdx.x & 63;
    int v = adj[(size_t)w * 64 + lane];
    unsigned long long m = __ballot(v > 0);
    if (lane == 0) mb[w] = m;
}

// ---------------- generic fp32 GEMM: C = A[MxK] * B[KxN] (+epilogue) ----------------
// EPI: 0 = none, 1 = bias+relu, 2 = bias+resid
#define BM 128
#define BN 64
#define BKK 16
template <int EPI, bool VECB>
__global__ __launch_bounds__(256) void k_gemm(const float* __restrict__ A, int lda,
                                              const float* __restrict__ B, int ldb,
                                              float* __restrict__ C, int ldc,
                                              int M, int N, int K, int Nstore,
                                              const float* __restrict__ bias,
                                              const float* __restrict__ resid, int ldr) {
    __shared__ float As[BKK][132];
    __shared__ float Bs[BKK][72];
    const int t = threadIdx.x;
    const int tx = t & 15;
    const int ty = t >> 4;
    const int m0 = blockIdx.x * BM;
    const int n0 = blockIdx.y * BN;
    float acc[8][4] = {};
    const int nkt = (K + BKK - 1) / BKK;
    for (int kt = 0; kt < nkt; ++kt) {
        const int k0 = kt * BKK;
        // A tile: 128 x 16 (store transposed As[k][m])
        #pragma unroll
        for (int jj = 0; jj < 2; ++jj) {
            int j = t + jj * 256;
            int row = j >> 2;
            int kc = (j & 3) * 4;
            int kk = k0 + kc;
            float4 v = make_float4(0.f, 0.f, 0.f, 0.f);
            const float* ap = &A[(size_t)(m0 + row) * lda + kk];
            if (kk + 4 <= K) v = *reinterpret_cast<const float4*>(ap);
            else {
                float* vv = reinterpret_cast<float*>(&v);
                #pragma unroll
                for (int e = 0; e < 4; ++e) if (kk + e < K) vv[e] = ap[e];
            }
            As[kc + 0][row] = v.x; As[kc + 1][row] = v.y;
            As[kc + 2][row] = v.z; As[kc + 3][row] = v.w;
        }
        // B tile: 16 x 64
        {
            int row = t >> 4;
            int c4 = (t & 15) * 4;
            float4 v = make_float4(0.f, 0.f, 0.f, 0.f);
            if (k0 + row < K) {
                const float* bp = &B[(size_t)(k0 + row) * ldb + n0 + c4];
                if (VECB && (n0 + c4 + 4 <= N)) v = *reinterpret_cast<const float4*>(bp);
                else {
                    float* vv = reinterpret_cast<float*>(&v);
                    #pragma unroll
                    for (int e = 0; e < 4; ++e) if (n0 + c4 + e < N) vv[e] = bp[e];
                }
            }
            *reinterpret_cast<float4*>(&Bs[row][c4]) = v;
        }
        __syncthreads();
        #pragma unroll
        for (int k = 0; k < BKK; ++k) {
            float4 a0 = *reinterpret_cast<const float4*>(&As[k][ty * 8]);
            float4 a1 = *reinterpret_cast<const float4*>(&As[k][ty * 8 + 4]);
            float4 b0 = *reinterpret_cast<const float4*>(&Bs[k][tx * 4]);
            float av[8] = {a0.x, a0.y, a0.z, a0.w, a1.x, a1.y, a1.z, a1.w};
            float bv[4] = {b0.x, b0.y, b0.z, b0.w};
            #pragma unroll
            for (int i = 0; i < 8; ++i)
                #pragma unroll
                for (int j = 0; j < 4; ++j) acc[i][j] += av[i] * bv[j];
        }
        __syncthreads();
    }
    // epilogue
    #pragma unroll
    for (int i = 0; i < 8; ++i) {
        int r = m0 + ty * 8 + i;
        #pragma unroll
        for (int j = 0; j < 4; ++j) {
            int c = n0 + tx * 4 + j;
            if (c < Nstore) {
                float v = acc[i][j];
                if constexpr (EPI == 1) v = fmaxf(v + bias[c], 0.0f);
                if constexpr (EPI == 2) v = v + bias[c] + resid[(size_t)r * ldr + c];
                C[(size_t)r * ldc + c] = v;
            }
        }
    }
}

// ---------------- f1/f2 attention scores: one wave per (h,n) ----------------
__global__ __launch_bounds__(256) void k_fscore(const float* __restrict__ Wh,
                                                const float* __restrict__ a,
                                                float* __restrict__ F1, float* __restrict__ F2) {
    int w = blockIdx.x * 4 + (threadIdx.x >> 6);   // (h,n) flat
    int lane = threadIdx.x & 63;
    int h = w >> 12;
    int n = w & 4095;
    const float* row = Wh + ((size_t)h * NTOT + n) * WHLD;
    const float* a1 = a + h * (2 * NHID_);
    const float* a2 = a1 + NHID_;
    float s1 = 0.f, s2 = 0.f;
    for (int d = lane; d < NHID_; d += 64) {
        float v = row[d];
        s1 += v * a1[d];
        s2 += v * a2[d];
    }
    #pragma unroll
    for (int off = 32; off; off >>= 1) {
        s1 += __shfl_down(s1, off);
        s2 += __shfl_down(s2, off);
    }
    if (lane == 0) { F1[w] = s1; F2[w] = s2; }
}

// ---------------- per-row softmax stats (max, denom), online ----------------
__global__ __launch_bounds__(256) void k_rowstat(const float* __restrict__ F1,
                                                 const float* __restrict__ F2,
                                                 const unsigned long long* __restrict__ mb,
                                                 float* __restrict__ RMAX, float* __restrict__ RDEN) {
    __shared__ float f2s[NTOT];
    __shared__ unsigned long long mw[4][64];
    int h = blockIdx.y;
    const float4* src = reinterpret_cast<const float4*>(F2 + (size_t)h * NTOT);
    float4* dst = reinterpret_cast<float4*>(f2s);
    for (int i = threadIdx.x; i < NTOT / 4; i += 256) dst[i] = src[i];
    int wv = threadIdx.x >> 6, lane = threadIdx.x & 63;
    int n = blockIdx.x * 4 + wv;
    mw[wv][lane] = mb[(size_t)n * 64 + lane];
    __syncthreads();
    float f1n = F1[(size_t)h * NTOT + n];
    float rm = -1e30f, rs = 0.f;
    for (int b = 0; b < 64; ++b) {
        unsigned long long wb = mw[wv][b];
        if ((wb >> lane) & 1ULL) {
            float e = f1n + f2s[b * 64 + lane];
            e = e > 0.f ? e : 0.2f * e;
            if (e > rm) { rs *= __expf(rm - e); rm = e; }
            rs += __expf(e - rm);
        }
    }
    #pragma unroll
    for (int off = 32; off; off >>= 1) {
        float m2 = __shfl_down(rm, off), s2 = __shfl_down(rs, off);
        float nm = fmaxf(rm, m2);
        rs = rs * __expf(rm - nm) + s2 * __expf(m2 - nm);
        rm = nm;
    }
    if (lane == 0) {
        if (rs == 0.f) rs = 1.f;   // unreachable for random adj; NaN guard
        RMAX[(size_t)h * NTOT + n] = rm;
        RDEN[(size_t)h * NTOT + n] = rs;
    }
}

// ---------------- attention PV: G[n, h*257+d] = elu(sum_m p[n,m] Wh[h,m,d]) ----------------
__global__ __launch_bounds__(256) void k_pv(const float* __restrict__ Wh,
                                            const float* __restrict__ F1,
                                            const float* __restrict__ F2,
                                            const float* __restrict__ RMAX,
                                            const float* __restrict__ RDEN,
                                            const unsigned long long* __restrict__ mb,
                                            float* __restrict__ G) {
    __shared__ float As[BKK][132];
    __shared__ float Bs[BKK][72];
    const int h = blockIdx.z;
    const int t = threadIdx.x;
    const int tx = t & 15, ty = t >> 4;
    const int n0 = blockIdx.x * BM;
    const int c0 = blockIdx.y * BN;
    const float* WhH = Wh + (size_t)h * NTOT * WHLD;
    const float* F2h = F2 + (size_t)h * NTOT;
    const int nloc = t & 127;
    const int k2 = t >> 7;                 // 0/1: which 8 k-rows this thread generates
    const int ng = n0 + nloc;
    const float f1n = F1[(size_t)h * NTOT + ng];
    const float rmx = RMAX[(size_t)h * NTOT + ng];
    const float pscale = 1.0f / RDEN[(size_t)h * NTOT + ng];
    const unsigned long long* mrow = mb + (size_t)ng * 64;
    float acc[8][4] = {};
    unsigned long long word = 0;
    for (int kt = 0; kt < NTOT / BKK; ++kt) {
        const int k0 = kt * BKK;
        if ((kt & 3) == 0) word = mrow[k0 >> 6];
        const int mbase = k0 + k2 * 8;
        #pragma unroll
        for (int e = 0; e < 8; ++e) {
            int m = mbase + e;
            float bit = ((word >> (m & 63)) & 1ULL) ? 1.0f : 0.0f;
            float ev = f1n + F2h[m];
            ev = ev > 0.f ? ev : 0.2f * ev;
            float p = bit * (__expf(ev - rmx) * pscale);
            As[k2 * 8 + e][nloc] = p;
        }
        {
            int row = t >> 4;
            int c4 = (t & 15) * 4;
            float4 v = make_float4(0.f, 0.f, 0.f, 0.f);
            if (c0 + c4 + 4 <= WHLD)
                v = *reinterpret_cast<const float4*>(&WhH[(size_t)(k0 + row) * WHLD + c0 + c4]);
            *reinterpret_cast<float4*>(&Bs[row][c4]) = v;
        }
        __syncthreads();
        #pragma unroll
        for (int k = 0; k < BKK; ++k) {
            float4 a0 = *reinterpret_cast<const float4*>(&As[k][ty * 8]);
            float4 a1 = *reinterpret_cast<const float4*>(&As[k][ty * 8 + 4]);
            float4 b0 = *reinterpret_cast<const float4*>(&Bs[k][tx * 4]);
            float av[8] = {a0.x, a0.y, a0.z, a0.w, a1.x, a1.y, a1.z, a1.w};
            float bv[4] = {b0.x, b0.y, b0.z, b0.w};
            #pragma unroll
            for (int i = 0; i < 8; ++i)
                #pragma unroll
                for (int j = 0; j < 4; ++j) acc[i][j] += av[i] * bv[j];
        }
        __syncthreads();
    }
    #pragma unroll
    for (int i = 0; i < 8; ++i) {
        int n = n0 + ty * 8 + i;
        #pragma unroll
        for (int j = 0; j < 4; ++j) {
            int c = c0 + tx * 4 + j;
            if (c < NHID_) {
                float v = acc[i][j];
                v = v > 0.f ? v : expm1f(v);   // elu
                G[(size_t)n * DCOLS + h * NHID_ + c] = v;
            }
        }
    }
}

// ---------------- LayerNorm (in-place safe) ----------------
__global__ __launch_bounds__(256) void k_ln(const float* __restrict__ T,
                                            const float* __restrict__ g,
                                            const float* __restrict__ b,
                                            float* __restrict__ O) {
    int n = blockIdx.x;
    const float* row = T + (size_t)n * DCOLS;
    float s = 0.f, q = 0.f;
    for (int i = threadIdx.x; i < DCOLS / 4; i += 256) {
        float4 v = *reinterpret_cast<const float4*>(&row[i * 4]);
        s += v.x + v.y + v.z + v.w;
        q += v.x * v.x + v.y * v.y + v.z * v.z + v.w * v.w;
    }
    __shared__ float ls[2][4];
    int lane = threadIdx.x & 63, wv = threadIdx.x >> 6;
    #pragma unroll
    for (int off = 32; off; off >>= 1) {
        s += __shfl_down(s, off);
        q += __shfl_down(q, off);
    }
    if (lane == 0) { ls[0][wv] = s; ls[1][wv] = q; }
    __syncthreads();
    s = ls[0][0] + ls[0][1] + ls[0][2] + ls[0][3];
    q = ls[1][0] + ls[1][1] + ls[1][2] + ls[1][3];
    float mean = s * (1.0f / DCOLS);
    float var = q * (1.0f / DCOLS) - mean * mean;
    float rstd = rsqrtf(var + 1e-5f);
    float* orow = O + (size_t)n * DCOLS;
    for (int i = threadIdx.x; i < DCOLS; i += 256)
        orow[i] = (row[i] - mean) * rstd * g[i] + b[i];
}

// ---------------- logits + sigmoid + per-row loss partial ----------------
__global__ __launch_bounds__(128) void k_logits(const float* __restrict__ X,
                                                const float* __restrict__ W,
                                                const float* __restrict__ bias,
                                                const float* __restrict__ Y,
                                                float* __restrict__ out,
                                                float* __restrict__ lossp) {
    __shared__ float xs[DCOLS];
    int n = blockIdx.x;
    for (int i = threadIdx.x; i < DCOLS / 4; i += 128)
        *reinterpret_cast<float4*>(&xs[i * 4]) =
            *reinterpret_cast<const float4*>(&X[(size_t)n * DCOLS + i * 4]);
    __syncthreads();
    float loss = 0.f;
    int c = threadIdx.x;
    if (c < 80) {
        float acc = bias[c];
        for (int k = 0; k < DCOLS; ++k) acc += xs[k] * W[k * 80 + c];
        out[n * 80 + c] = 1.0f / (1.0f + expf(-acc));
        float y = Y[n * 80 + c];
        loss = fmaxf(acc, 0.f) - acc * y + log1pf(expf(-fabsf(acc)));
    }
    __shared__ float lr[2];
    int lane = threadIdx.x & 63, wv = threadIdx.x >> 6;
    #pragma unroll
    for (int off = 32; off; off >>= 1) loss += __shfl_down(loss, off);
    if (lane == 0) lr[wv] = loss;
    __syncthreads();
    if (threadIdx.x == 0) lossp[n] = lr[0] + lr[1];
}

__global__ __launch_bounds__(256) void k_lossfin(const float* __restrict__ lossp,
                                                 float* __restrict__ out) {
    float s = 0.f;
    for (int i = threadIdx.x; i < NACT; i += 256) s += lossp[i];
    #pragma unroll
    for (int off = 32; off; off >>= 1) s += __shfl_down(s, off);
    __shared__ float lr[4];
    int lane = threadIdx.x & 63, wv = threadIdx.x >> 6;
    if (lane == 0) lr[wv] = s;
    __syncthreads();
    if (threadIdx.x == 0) out[NACT * 80] = (lr[0] + lr[1] + lr[2] + lr[3]) / (float)(NACT * 80);
}

// ---------------- host launcher ----------------
extern "C" void kernel_launch(void* const* d_in, const int* in_sizes, int n_in,
                              void* d_out, int out_size, void* d_ws, size_t ws_size,
                              hipStream_t stream) {
    const float* actors_features  = (const float*)d_in[0];
    const float* actors_labels    = (const float*)d_in[1];
    const float* actors_boxes     = (const float*)d_in[2];
    const float* objects_features = (const float*)d_in[3];
    const float* objects_boxes    = (const float*)d_in[4];
    const int*   adj              = (const int*)d_in[5];
    const float* obj_W    = (const float*)d_in[6];
    const float* obj_b    = (const float*)d_in[7];
    const float* gatW[2]  = {(const float*)d_in[8],  (const float*)d_in[14]};
    const float* gatA[2]  = {(const float*)d_in[9],  (const float*)d_in[15]};
    const float* fcW[2]   = {(const float*)d_in[10], (const float*)d_in[16]};
    const float* fcB[2]   = {(const float*)d_in[11], (const float*)d_in[17]};
    const float* lnG[2]   = {(const float*)d_in[12], (const float*)d_in[18]};
    const float* lnB[2]   = {(const float*)d_in[13], (const float*)d_in[19]};
    const float* logits_W = (const float*)d_in[20];
    const float* logits_b = (const float*)d_in[21];
    float* out = (float*)d_out;

    float* ws   = (float*)d_ws;
    float* X0   = ws + OFF_X0;
    float* G    = ws + OFF_G;
    float* T    = ws + OFF_T;
    float* WH   = ws + OFF_WH;
    float* F1   = ws + OFF_F1;
    float* F2   = ws + OFF_F2;
    float* RMAX = ws + OFF_RMAX;
    float* RDEN = ws + OFF_RDEN;
    float* LOSSP= ws + OFF_LOSSP;
    unsigned long long* MASK = (unsigned long long*)(ws + OFF_MASK);

    k_geo<<<(NTOT + 255) / 256, 256, 0, stream>>>(actors_boxes, objects_boxes, X0);
    k_meanpool<<<(NACT * 1024) / 4, 256, 0, stream>>>(actors_features, X0);
    k_packmask<<<(NTOT * 64) / 4, 256, 0, stream>>>(adj, MASK);
    // objects reducer: relu(of @ obj_W + b) -> X0 rows [512, 4096), cols [0,1024)
    k_gemm<1, true><<<dim3(NOBJ / BM, 1024 / BN), 256, 0, stream>>>(
        objects_features, OFSZ, obj_W, 1024, X0 + (size_t)NACT * DCOLS, DCOLS,
        NOBJ, 1024, OFSZ, 1024, obj_b, nullptr, 0);

    const float* xin = X0;
    for (int L = 0; L < 2; ++L) {
        for (int h = 0; h < 4; ++h)
            k_gemm<0, false><<<dim3(NTOT / BM, 5), 256, 0, stream>>>(
                xin, DCOLS, gatW[L] + (size_t)h * DCOLS * NHID_, NHID_,
                WH + (size_t)h * NTOT * WHLD, WHLD,
                NTOT, NHID_, DCOLS, WHLD, nullptr, nullptr, 0);
        k_fscore<<<(4 * NTOT) / 4, 256, 0, stream>>>(WH, gatA[L], F1, F2);
        k_rowstat<<<dim3(NTOT / 4, 4), 256, 0, stream>>>(F1, F2, MASK, RMAX, RDEN);
        k_pv<<<dim3(NTOT / BM, 5, 4), 256, 0, stream>>>(WH, F1, F2, RMAX, RDEN, MASK, G);
        k_gemm<2, true><<<dim3(NTOT / BM, 17), 256, 0, stream>>>(
            G, DCOLS, fcW[L], DCOLS, T, DCOLS,
            NTOT, DCOLS, DCOLS, DCOLS, fcB[L], xin, DCOLS);
        k_ln<<<NTOT, 256, 0, stream>>>(T, lnG[L], lnB[L], T);
        xin = T;
    }
    k_logits<<<NACT, 128, 0, stream>>>(T, logits_W, logits_b, actors_labels, out, LOSSP);
    k_lossfin<<<1, 256, 0, stream>>>(LOSSP, out);
}

// Round 2
// 1599.258 us; speedup vs baseline: 2.5694x; 2.5694x over previous
//
#include <hip/hip_runtime.h>
#include <cstdint>

#define NACT 512
#define NOBJ 3584
#define NTOT 4096
#define DCOLS 1028
#define NHID_ 257
#define OFSZ 2048
#define KPAD 1056          // padded D for bf16 GEMM K
#define NPADH 320          // padded per-head hidden (5 x 64)
#define NPADFC 1088        // padded fc out cols (17 x 64)

typedef float f32x4 __attribute__((ext_vector_type(4)));
typedef short short8v __attribute__((ext_vector_type(8)));
typedef short short4v __attribute__((ext_vector_type(4)));

// ---- workspace layout (float offsets) ----
static const size_t OFF_X0    = 0;                                   // 4096x1028 f32
static const size_t OFF_T     = 4210688;                             // 4096x1028 f32
static const size_t OFF_F1    = 8421376;                             // 4x4096 f32
static const size_t OFF_F2    = 8437760;
static const size_t OFF_RMAX  = 8454144;
static const size_t OFF_RDEN  = 8470528;
static const size_t OFF_LOSSP = 8486912;                             // 512
static const size_t OFF_MASK  = 8487424;                             // 4096x64 u64 (524288 f)
static const size_t OFF_XB    = 9011712;                             // 4096x1056 bf16
static const size_t OFF_GB    = 11174400;                            // 4096x1056 bf16
static const size_t OFF_OBJWT = 13337088;                            // 1024x2048 bf16
static const size_t OFF_GATWT = 14385664;                            // 8 x 320x1056 bf16
static const size_t OFF_FCWT  = 15737344;                            // 2 x 1088x1056 bf16
static const size_t OFF_WHT   = 16886272;                            // 4 x 320x4096 bf16

__device__ __forceinline__ short f2bf(float x) {
    unsigned u = __float_as_uint(x);
    u += 0x7fffu + ((u >> 16) & 1u);
    return (short)(u >> 16);
}
// byte offset inside a [rows][32 bf16] LDS tile, XOR-swizzled 16B chunks
__device__ __forceinline__ int swz(int row, int chunk) {
    return row * 64 + (((chunk ^ ((row >> 1) & 3))) << 4);
}

// ---------------- geo features ----------------
__global__ void k_geo(const float* __restrict__ ab, const float* __restrict__ ob,
                      float* __restrict__ X) {
    int n = blockIdx.x * blockDim.x + threadIdx.x;
    if (n >= NTOT) return;
    const float* b = (n < NACT) ? &ab[n * 4] : &ob[(n - NACT) * 4];
    float x0 = b[0], y0 = b[1], x1 = b[2], y1 = b[3];
    float* o = &X[(size_t)n * DCOLS + 1024];
    o[0] = y1 - y0;
    o[1] = x1 - x0;
    o[2] = (x1 - x0) * 0.5f + x0;
    o[3] = (y1 - y0) * 0.5f + y0;
}

// ---------------- mean-pool 196 -> 1 ----------------
__global__ __launch_bounds__(256) void k_meanpool(const float* __restrict__ af,
                                                  float* __restrict__ X) {
    int w = blockIdx.x * 4 + (threadIdx.x >> 6);
    int lane = threadIdx.x & 63;
    const float* src = af + (size_t)w * 196;
    float s = src[lane] + src[lane + 64] + src[lane + 128];
    if (lane < 4) s += src[192 + lane];
    #pragma unroll
    for (int off = 32; off; off >>= 1) s += __shfl_down(s, off);
    if (lane == 0) {
        int n = w >> 10, c = w & 1023;
        X[(size_t)n * DCOLS + c] = s * (1.0f / 196.0f);
    }
}

// ---------------- pack adjacency into bitmask ----------------
__global__ __launch_bounds__(256) void k_packmask(const int* __restrict__ adj,
                                                  unsigned long long* __restrict__ mb) {
    int w = blockIdx.x * 4 + (threadIdx.x >> 6);
    int lane = threadIdx.x & 63;
    int v = adj[(size_t)w * 64 + lane];
    unsigned long long m = __ballot(v > 0);
    if (lane == 0) mb[w] = m;
}

// ---------------- transpose + convert weights: W[K][N] f32 -> Wt[Npad][Kpad] bf16 ----------------
__global__ __launch_bounds__(256) void k_transpW(const float* __restrict__ W, int K, int N,
                                                 short* __restrict__ Wt, int Kpad, int Npad) {
    __shared__ float Ws[32][33];
    int k0 = blockIdx.x * 32, n0 = blockIdx.y * 32;
    int t = threadIdx.x;
    #pragma unroll
    for (int i = 0; i < 4; ++i) {
        int j = t + i * 256;
        int r = j >> 5, c = j & 31;
        float v = 0.f;
        if (k0 + r < K && n0 + c < N) v = W[(size_t)(k0 + r) * N + n0 + c];
        Ws[r][c] = v;
    }
    __syncthreads();
    #pragma unroll
    for (int i = 0; i < 4; ++i) {
        int j = t + i * 256;
        int n = j >> 5, k = j & 31;
        Wt[(size_t)(n0 + n) * Kpad + k0 + k] = f2bf(Ws[k][n]);
    }
}

// ---------------- convert fp32 [4096][1028] -> bf16 [4096][1056] (zero pad) ----------------
__global__ __launch_bounds__(256) void k_convX(const float* __restrict__ X,
                                               short* __restrict__ Xb) {
    int i = blockIdx.x * 256 + threadIdx.x;      // 4096*132 total
    int n = i / 132, g = i % 132;
    int c0 = g * 8;
    short8v o;
    if (c0 + 8 <= DCOLS) {
        float4 v0 = *reinterpret_cast<const float4*>(&X[(size_t)n * DCOLS + c0]);
        float4 v1 = *reinterpret_cast<const float4*>(&X[(size_t)n * DCOLS + c0 + 4]);
        o[0]=f2bf(v0.x); o[1]=f2bf(v0.y); o[2]=f2bf(v0.z); o[3]=f2bf(v0.w);
        o[4]=f2bf(v1.x); o[5]=f2bf(v1.y); o[6]=f2bf(v1.z); o[7]=f2bf(v1.w);
    } else {
        #pragma unroll
        for (int j = 0; j < 8; ++j)
            o[j] = (c0 + j < DCOLS) ? f2bf(X[(size_t)n * DCOLS + c0 + j]) : (short)0;
    }
    *reinterpret_cast<short8v*>(&Xb[(size_t)n * KPAD + c0]) = o;
}

// ---------------- unified bf16 MFMA GEMM ----------------
// MODE 0: obj   A=f32 global, epi: relu(acc+bias) -> f32 C
// MODE 1: wh    A=bf16 global, epi: bf16 C^T (WHT) + fused f1/f2 atomics
// MODE 2: pv    A=generated P, epi: elu -> bf16 Gb cols z*257+d
// MODE 3: fc    A=bf16 global, epi: acc+bias+resid -> f32 C
template <int MODE>
__global__ __launch_bounds__(256) void k_mm(
    const void* __restrict__ Aptr, int lda,
    const short* __restrict__ Bt, int ldb,
    void* __restrict__ Cptr, int ldc,
    const float* __restrict__ bias,
    const float* __restrict__ resid, int ldr,
    float* __restrict__ F1, float* __restrict__ F2,
    const float* __restrict__ RMAX, const float* __restrict__ RDEN,
    const unsigned long long* __restrict__ MB,
    const float* __restrict__ AV,
    int nk, int Nvalid) {
    __shared__ char sm[12288];                 // As: [128][32]bf16 @0, Bs: [64][32]bf16 @8192
    const int t = threadIdx.x;
    const int m0 = blockIdx.x * 128;
    const int n0 = blockIdx.y * 64;
    const int z = blockIdx.z;

    short* Cwh = nullptr;
    short* Cgb = nullptr;
    float* Cf  = nullptr;
    int gcol = 0;
    if constexpr (MODE == 1) {
        Bt += (size_t)z * (NPADH * KPAD);
        Cwh = (short*)Cptr + (size_t)z * (NPADH * NTOT);
        AV += z * (2 * NHID_);
        F1 += z * NTOT; F2 += z * NTOT;
    } else if constexpr (MODE == 2) {
        Bt += (size_t)z * (NPADH * NTOT);
        F1 += z * NTOT; F2 += z * NTOT;
        RMAX += z * NTOT; RDEN += z * NTOT;
        Cgb = (short*)Cptr;
        gcol = z * NHID_;
    } else {
        Cf = (float*)Cptr;
    }

    // staging indices
    const int ar = t >> 1, acp = t & 1;        // A: row, chunk-pair
    const int bn = t >> 2, bc = t & 3;         // B: n-row, chunk
    // PV generation state
    float f1n = 0.f, rmx = 0.f, psc = 0.f;
    const unsigned long long* mrow = nullptr;
    const int pr = t & 127, pmh = t >> 7;
    if constexpr (MODE == 2) {
        int n = m0 + pr;
        f1n = F1[n];
        rmx = RMAX[n];
        psc = 1.0f / RDEN[n];
        mrow = MB + (size_t)n * 64;
    }

    // mfma lane geometry
    const int wv = t >> 6, lane = t & 63, lr = lane & 15, lk = lane >> 4;
    const int aoff0 = swz(32 * wv + lr, lk);
    const int aoff1 = swz(32 * wv + 16 + lr, lk);
    int boff[4];
    #pragma unroll
    for (int cb = 0; cb < 4; ++cb) boff[cb] = 8192 + swz(16 * cb + lr, lk);

    f32x4 acc[2][4];
    #pragma unroll
    for (int i = 0; i < 2; ++i)
        #pragma unroll
        for (int j = 0; j < 4; ++j) acc[i][j] = (f32x4){0.f, 0.f, 0.f, 0.f};

    for (int kt = 0; kt < nk; ++kt) {
        const int k0 = kt * 32;
        // ---- stage A ----
        if constexpr (MODE == 0) {
            const float* ap = (const float*)Aptr + (size_t)(m0 + ar) * lda + k0 + acp * 16;
            float4 u0 = *reinterpret_cast<const float4*>(ap);
            float4 u1 = *reinterpret_cast<const float4*>(ap + 4);
            float4 u2 = *reinterpret_cast<const float4*>(ap + 8);
            float4 u3 = *reinterpret_cast<const float4*>(ap + 12);
            short8v s0, s1;
            s0[0]=f2bf(u0.x); s0[1]=f2bf(u0.y); s0[2]=f2bf(u0.z); s0[3]=f2bf(u0.w);
            s0[4]=f2bf(u1.x); s0[5]=f2bf(u1.y); s0[6]=f2bf(u1.z); s0[7]=f2bf(u1.w);
            s1[0]=f2bf(u2.x); s1[1]=f2bf(u2.y); s1[2]=f2bf(u2.z); s1[3]=f2bf(u2.w);
            s1[4]=f2bf(u3.x); s1[5]=f2bf(u3.y); s1[6]=f2bf(u3.z); s1[7]=f2bf(u3.w);
            *reinterpret_cast<short8v*>(sm + swz(ar, 2 * acp)) = s0;
            *reinterpret_cast<short8v*>(sm + swz(ar, 2 * acp + 1)) = s1;
        } else if constexpr (MODE == 1 || MODE == 3) {
            const short* ap = (const short*)Aptr + (size_t)(m0 + ar) * lda + k0 + acp * 16;
            short8v v0 = *reinterpret_cast<const short8v*>(ap);
            short8v v1 = *reinterpret_cast<const short8v*>(ap + 8);
            *reinterpret_cast<short8v*>(sm + swz(ar, 2 * acp)) = v0;
            *reinterpret_cast<short8v*>(sm + swz(ar, 2 * acp + 1)) = v1;
        } else {
            // generate P row pr, m in [k0+16*pmh, +16)
            const int mk = k0 + pmh * 16;
            unsigned long long w = mrow[mk >> 6];
            const int bb = mk & 63;
            const float* F2k = F2 + mk;
            float4 q0 = *reinterpret_cast<const float4*>(F2k);
            float4 q1 = *reinterpret_cast<const float4*>(F2k + 4);
            float4 q2 = *reinterpret_cast<const float4*>(F2k + 8);
            float4 q3 = *reinterpret_cast<const float4*>(F2k + 12);
            float fv[16] = {q0.x,q0.y,q0.z,q0.w, q1.x,q1.y,q1.z,q1.w,
                            q2.x,q2.y,q2.z,q2.w, q3.x,q3.y,q3.z,q3.w};
            short8v o0, o1;
            #pragma unroll
            for (int j = 0; j < 8; ++j) {
                float e = f1n + fv[j];
                e = e > 0.f ? e : 0.2f * e;
                float p = ((w >> (bb + j)) & 1ULL) ? __expf(e - rmx) * psc : 0.f;
                o0[j] = f2bf(p);
            }
            #pragma unroll
            for (int j = 0; j < 8; ++j) {
                float e = f1n + fv[8 + j];
                e = e > 0.f ? e : 0.2f * e;
                float p = ((w >> (bb + 8 + j)) & 1ULL) ? __expf(e - rmx) * psc : 0.f;
                o1[j] = f2bf(p);
            }
            *reinterpret_cast<short8v*>(sm + swz(pr, 2 * pmh)) = o0;
            *reinterpret_cast<short8v*>(sm + swz(pr, 2 * pmh + 1)) = o1;
        }
        // ---- stage B ----
        {
            const short* bp = Bt + (size_t)(n0 + bn) * ldb + k0 + bc * 8;
            short8v v = *reinterpret_cast<const short8v*>(bp);
            *reinterpret_cast<short8v*>(sm + 8192 + swz(bn, bc)) = v;
        }
        __syncthreads();
        // ---- MFMA ----
        short8v a0 = *reinterpret_cast<short8v*>(sm + aoff0);
        short8v a1 = *reinterpret_cast<short8v*>(sm + aoff1);
        #pragma unroll
        for (int cb = 0; cb < 4; ++cb) {
            short8v b = *reinterpret_cast<short8v*>(sm + boff[cb]);
            acc[0][cb] = __builtin_amdgcn_mfma_f32_16x16x32_bf16(a0, b, acc[0][cb], 0, 0, 0);
            acc[1][cb] = __builtin_amdgcn_mfma_f32_16x16x32_bf16(a1, b, acc[1][cb], 0, 0, 0);
        }
        __syncthreads();
    }

    // ---- epilogue ----
    const int mb0 = m0 + 32 * wv + 4 * lk;
    if constexpr (MODE == 0 || MODE == 3) {
        #pragma unroll
        for (int rb = 0; rb < 2; ++rb)
            #pragma unroll
            for (int cb = 0; cb < 4; ++cb) {
                int c = n0 + 16 * cb + lr;
                if (c < Nvalid) {
                    #pragma unroll
                    for (int rr = 0; rr < 4; ++rr) {
                        int m = mb0 + 16 * rb + rr;
                        float v = acc[rb][cb][rr] + bias[c];
                        if constexpr (MODE == 0) v = fmaxf(v, 0.f);
                        if constexpr (MODE == 3) v += resid[(size_t)m * ldr + c];
                        Cf[(size_t)m * ldc + c] = v;
                    }
                }
            }
    } else if constexpr (MODE == 1) {
        float la1[4], la2[4];
        #pragma unroll
        for (int cb = 0; cb < 4; ++cb) {
            int d = n0 + 16 * cb + lr;
            la1[cb] = (d < NHID_) ? AV[d] : 0.f;
            la2[cb] = (d < NHID_) ? AV[NHID_ + d] : 0.f;
        }
        #pragma unroll
        for (int rb = 0; rb < 2; ++rb) {
            #pragma unroll
            for (int cb = 0; cb < 4; ++cb) {
                int d = n0 + 16 * cb + lr;
                short4v o;
                o[0] = f2bf(acc[rb][cb][0]); o[1] = f2bf(acc[rb][cb][1]);
                o[2] = f2bf(acc[rb][cb][2]); o[3] = f2bf(acc[rb][cb][3]);
                *reinterpret_cast<short4v*>(&Cwh[(size_t)d * NTOT + mb0 + 16 * rb]) = o;
            }
            #pragma unroll
            for (int rr = 0; rr < 4; ++rr) {
                float s1 = 0.f, s2 = 0.f;
                #pragma unroll
                for (int cb = 0; cb < 4; ++cb) {
                    s1 += acc[rb][cb][rr] * la1[cb];
                    s2 += acc[rb][cb][rr] * la2[cb];
                }
                #pragma unroll
                for (int mk = 1; mk < 16; mk <<= 1) {
                    s1 += __shfl_xor(s1, mk);
                    s2 += __shfl_xor(s2, mk);
                }
                if (lr == 0) {
                    int m = mb0 + 16 * rb + rr;
                    atomicAdd(&F1[m], s1);
                    atomicAdd(&F2[m], s2);
                }
            }
        }
    } else {  // MODE 2: PV
        #pragma unroll
        for (int rb = 0; rb < 2; ++rb)
            #pragma unroll
            for (int cb = 0; cb < 4; ++cb) {
                int d = n0 + 16 * cb + lr;
                if (d < NHID_) {
                    #pragma unroll
                    for (int rr = 0; rr < 4; ++rr) {
                        int m = mb0 + 16 * rb + rr;
                        float v = acc[rb][cb][rr];
                        v = v > 0.f ? v : expm1f(v);
                        Cgb[(size_t)m * KPAD + gcol + d] = f2bf(v);
                    }
                }
            }
    }
}

// ---------------- per-row softmax stats (max, denom), online ----------------
__global__ __launch_bounds__(256) void k_rowstat(const float* __restrict__ F1,
                                                 const float* __restrict__ F2,
                                                 const unsigned long long* __restrict__ mb,
                                                 float* __restrict__ RMAX, float* __restrict__ RDEN) {
    __shared__ float f2s[NTOT];
    __shared__ unsigned long long mw[4][64];
    int h = blockIdx.y;
    const float4* src = reinterpret_cast<const float4*>(F2 + (size_t)h * NTOT);
    float4* dst = reinterpret_cast<float4*>(f2s);
    for (int i = threadIdx.x; i < NTOT / 4; i += 256) dst[i] = src[i];
    int wv = threadIdx.x >> 6, lane = threadIdx.x & 63;
    int n = blockIdx.x * 4 + wv;
    mw[wv][lane] = mb[(size_t)n * 64 + lane];
    __syncthreads();
    float f1n = F1[(size_t)h * NTOT + n];
    float rm = -1e30f, rs = 0.f;
    for (int b = 0; b < 64; ++b) {
        unsigned long long wb = mw[wv][b];
        if ((wb >> lane) & 1ULL) {
            float e = f1n + f2s[b * 64 + lane];
            e = e > 0.f ? e : 0.2f * e;
            if (e > rm) { rs *= __expf(rm - e); rm = e; }
            rs += __expf(e - rm);
        }
    }
    #pragma unroll
    for (int off = 32; off; off >>= 1) {
        float m2 = __shfl_down(rm, off), s2 = __shfl_down(rs, off);
        float nm = fmaxf(rm, m2);
        rs = rs * __expf(rm - nm) + s2 * __expf(m2 - nm);
        rm = nm;
    }
    if (lane == 0) {
        if (rs == 0.f) rs = 1.f;
        RMAX[(size_t)h * NTOT + n] = rm;
        RDEN[(size_t)h * NTOT + n] = rs;
    }
}

// ---------------- LayerNorm (in-place safe) ----------------
__global__ __launch_bounds__(256) void k_ln(const float* __restrict__ T,
                                            const float* __restrict__ g,
                                            const float* __restrict__ b,
                                            float* __restrict__ O) {
    int n = blockIdx.x;
    const float* row = T + (size_t)n * DCOLS;
    float s = 0.f, q = 0.f;
    for (int i = threadIdx.x; i < DCOLS / 4; i += 256) {
        float4 v = *reinterpret_cast<const float4*>(&row[i * 4]);
        s += v.x + v.y + v.z + v.w;
        q += v.x * v.x + v.y * v.y + v.z * v.z + v.w * v.w;
    }
    __shared__ float ls[2][4];
    int lane = threadIdx.x & 63, wv = threadIdx.x >> 6;
    #pragma unroll
    for (int off = 32; off; off >>= 1) {
        s += __shfl_down(s, off);
        q += __shfl_down(q, off);
    }
    if (lane == 0) { ls[0][wv] = s; ls[1][wv] = q; }
    __syncthreads();
    s = ls[0][0] + ls[0][1] + ls[0][2] + ls[0][3];
    q = ls[1][0] + ls[1][1] + ls[1][2] + ls[1][3];
    float mean = s * (1.0f / DCOLS);
    float var = q * (1.0f / DCOLS) - mean * mean;
    float rstd = rsqrtf(var + 1e-5f);
    float* orow = O + (size_t)n * DCOLS;
    for (int i = threadIdx.x; i < DCOLS; i += 256)
        orow[i] = (row[i] - mean) * rstd * g[i] + b[i];
}

// ---------------- logits + sigmoid + per-row loss partial ----------------
__global__ __launch_bounds__(128) void k_logits(const float* __restrict__ X,
                                                const float* __restrict__ W,
                                                const float* __restrict__ bias,
                                                const float* __restrict__ Y,
                                                float* __restrict__ out,
                                                float* __restrict__ lossp) {
    __shared__ float xs[DCOLS];
    int n = blockIdx.x;
    for (int i = threadIdx.x; i < DCOLS / 4; i += 128)
        *reinterpret_cast<float4*>(&xs[i * 4]) =
            *reinterpret_cast<const float4*>(&X[(size_t)n * DCOLS + i * 4]);
    __syncthreads();
    float loss = 0.f;
    int c = threadIdx.x;
    if (c < 80) {
        float acc = bias[c];
        for (int k = 0; k < DCOLS; ++k) acc += xs[k] * W[k * 80 + c];
        out[n * 80 + c] = 1.0f / (1.0f + expf(-acc));
        float y = Y[n * 80 + c];
        loss = fmaxf(acc, 0.f) - acc * y + log1pf(expf(-fabsf(acc)));
    }
    __shared__ float lr[2];
    int lane = threadIdx.x & 63, wv = threadIdx.x >> 6;
    #pragma unroll
    for (int off = 32; off; off >>= 1) loss += __shfl_down(loss, off);
    if (lane == 0) lr[wv] = loss;
    __syncthreads();
    if (threadIdx.x == 0) lossp[n] = lr[0] + lr[1];
}

__global__ __launch_bounds__(256) void k_lossfin(const float* __restrict__ lossp,
                                                 float* __restrict__ out) {
    float s = 0.f;
    for (int i = threadIdx.x; i < NACT; i += 256) s += lossp[i];
    #pragma unroll
    for (int off = 32; off; off >>= 1) s += __shfl_down(s, off);
    __shared__ float lr[4];
    int lane = threadIdx.x & 63, wv = threadIdx.x >> 6;
    if (lane == 0) lr[wv] = s;
    __syncthreads();
    if (threadIdx.x == 0) out[NACT * 80] = (lr[0] + lr[1] + lr[2] + lr[3]) / (float)(NACT * 80);
}

// ---------------- host launcher ----------------
extern "C" void kernel_launch(void* const* d_in, const int* in_sizes, int n_in,
                              void* d_out, int out_size, void* d_ws, size_t ws_size,
                              hipStream_t stream) {
    const float* actors_features  = (const float*)d_in[0];
    const float* actors_labels    = (const float*)d_in[1];
    const float* actors_boxes     = (const float*)d_in[2];
    const float* objects_features = (const float*)d_in[3];
    const float* objects_boxes    = (const float*)d_in[4];
    const int*   adj              = (const int*)d_in[5];
    const float* obj_W    = (const float*)d_in[6];
    const float* obj_b    = (const float*)d_in[7];
    const float* gatW[2]  = {(const float*)d_in[8],  (const float*)d_in[14]};
    const float* gatA[2]  = {(const float*)d_in[9],  (const float*)d_in[15]};
    const float* fcW[2]   = {(const float*)d_in[10], (const float*)d_in[16]};
    const float* fcB[2]   = {(const float*)d_in[11], (const float*)d_in[17]};
    const float* lnG[2]   = {(const float*)d_in[12], (const float*)d_in[18]};
    const float* lnB[2]   = {(const float*)d_in[13], (const float*)d_in[19]};
    const float* logits_W = (const float*)d_in[20];
    const float* logits_b = (const float*)d_in[21];
    float* out = (float*)d_out;

    float* ws   = (float*)d_ws;
    float* X0   = ws + OFF_X0;
    float* T    = ws + OFF_T;
    float* F1   = ws + OFF_F1;
    float* F2   = ws + OFF_F2;
    float* RMAX = ws + OFF_RMAX;
    float* RDEN = ws + OFF_RDEN;
    float* LOSSP= ws + OFF_LOSSP;
    unsigned long long* MASK = (unsigned long long*)(ws + OFF_MASK);
    short* Xb    = (short*)(ws + OFF_XB);
    short* Gb    = (short*)(ws + OFF_GB);
    short* objWt = (short*)(ws + OFF_OBJWT);
    short* gatWt = (short*)(ws + OFF_GATWT);
    short* fcWt  = (short*)(ws + OFF_FCWT);
    short* WHT   = (short*)(ws + OFF_WHT);

    hipMemsetAsync(F1, 0, 2 * 4 * NTOT * sizeof(float), stream);       // F1+F2
    hipMemsetAsync(Gb, 0, (size_t)NTOT * KPAD * 2, stream);

    k_geo<<<(NTOT + 255) / 256, 256, 0, stream>>>(actors_boxes, objects_boxes, X0);
    k_meanpool<<<(NACT * 1024) / 4, 256, 0, stream>>>(actors_features, X0);
    k_packmask<<<(NTOT * 64) / 4, 256, 0, stream>>>(adj, MASK);

    // weight transposes (bf16, padded)
    k_transpW<<<dim3(64, 32), 256, 0, stream>>>(obj_W, OFSZ, 1024, objWt, OFSZ, 1024);
    for (int L = 0; L < 2; ++L) {
        for (int h = 0; h < 4; ++h)
            k_transpW<<<dim3(33, 10), 256, 0, stream>>>(
                gatW[L] + (size_t)h * DCOLS * NHID_, DCOLS, NHID_,
                gatWt + (size_t)(L * 4 + h) * NPADH * KPAD, KPAD, NPADH);
        k_transpW<<<dim3(33, 34), 256, 0, stream>>>(
            fcW[L], DCOLS, DCOLS, fcWt + (size_t)L * NPADFC * KPAD, KPAD, NPADFC);
    }

    // objects reducer: relu(of @ obj_W + b) -> X0 rows [512,4096) cols [0,1024)
    k_mm<0><<<dim3(NOBJ / 128, 16, 1), 256, 0, stream>>>(
        objects_features, OFSZ, objWt, OFSZ, X0 + (size_t)NACT * DCOLS, DCOLS,
        obj_b, nullptr, 0, nullptr, nullptr, nullptr, nullptr, nullptr, nullptr,
        OFSZ / 32, 1024);

    k_convX<<<(NTOT * 132) / 256, 256, 0, stream>>>(X0, Xb);

    const float* xin = X0;
    for (int L = 0; L < 2; ++L) {
        if (L == 1)
            hipMemsetAsync(F1, 0, 2 * 4 * NTOT * sizeof(float), stream);
        if (L == 1)
            k_convX<<<(NTOT * 132) / 256, 256, 0, stream>>>(T, Xb);
        // Wh GEMM + fused f1/f2
        k_mm<1><<<dim3(NTOT / 128, NPADH / 64, 4), 256, 0, stream>>>(
            Xb, KPAD, gatWt + (size_t)L * 4 * NPADH * KPAD, KPAD, WHT, 0,
            nullptr, nullptr, 0, F1, F2, nullptr, nullptr, nullptr, gatA[L],
            KPAD / 32, NHID_);
        k_rowstat<<<dim3(NTOT / 4, 4), 256, 0, stream>>>(F1, F2, MASK, RMAX, RDEN);
        // PV
        k_mm<2><<<dim3(NTOT / 128, NPADH / 64, 4), 256, 0, stream>>>(
            nullptr, 0, WHT, NTOT, Gb, 0,
            nullptr, nullptr, 0, F1, F2, RMAX, RDEN, MASK, nullptr,
            NTOT / 32, NHID_);
        // fc + bias + resid
        k_mm<3><<<dim3(NTOT / 128, NPADFC / 64, 1), 256, 0, stream>>>(
            Gb, KPAD, fcWt + (size_t)L * NPADFC * KPAD, KPAD, T, DCOLS,
            fcB[L], xin, DCOLS, nullptr, nullptr, nullptr, nullptr, nullptr, nullptr,
            KPAD / 32, DCOLS);
        k_ln<<<NTOT, 256, 0, stream>>>(T, lnG[L], lnB[L], T);
        xin = T;
    }
    k_logits<<<NACT, 128, 0, stream>>>(T, logits_W, logits_b, actors_labels, out, LOSSP);
    k_lossfin<<<1, 256, 0, stream>>>(LOSSP, out);
}

// Round 3
// 1558.104 us; speedup vs baseline: 2.6372x; 1.0264x over previous
//
#include <hip/hip_runtime.h>
#include <cstdint>

#define NACT 512
#define NOBJ 3584
#define NTOT 4096
#define DCOLS 1028
#define NHID_ 257
#define OFSZ 2048
#define KPAD 1056          // padded D for bf16 GEMM K
#define NPADH 384          // padded per-head hidden (3 x 128)
#define NPADFC 1152        // padded fc out cols (9 x 128)

typedef float f32x4 __attribute__((ext_vector_type(4)));
typedef short short8v __attribute__((ext_vector_type(8)));
typedef short short4v __attribute__((ext_vector_type(4)));

// ---- workspace layout (float offsets) ----
static const size_t OFF_X0    = 0;                                   // 4096x1028 f32
static const size_t OFF_T     = 4210688;                             // 4096x1028 f32
static const size_t OFF_F1    = 8421376;                             // 4x4096 f32
static const size_t OFF_F2    = 8437760;
static const size_t OFF_RMAX  = 8454144;
static const size_t OFF_RDEN  = 8470528;
static const size_t OFF_LOSSP = 8486912;                             // 512
static const size_t OFF_MASK  = 8487424;                             // 4096x64 u64 (524288 f)
static const size_t OFF_XB    = 9011712;                             // 4096x1056 bf16
static const size_t OFF_GB    = 11174400;                            // 4096x1056 bf16
static const size_t OFF_OBJWT = 13337088;                            // 1024x2048 bf16
static const size_t OFF_GATWT = 14385664;                            // 8 x 384x1056 bf16
static const size_t OFF_FCWT  = 16007680;                            // 2 x 1152x1056 bf16
static const size_t OFF_WHT   = 17224192;                            // 4 x 384x4096 bf16 (ends 20369920 f)

__device__ __forceinline__ short f2bf(float x) {
    unsigned u = __float_as_uint(x);
    u += 0x7fffu + ((u >> 16) & 1u);
    return (short)(u >> 16);
}
// byte offset inside a [rows][32 bf16] LDS tile, XOR-swizzled 16B chunks
__device__ __forceinline__ int swz(int row, int chunk) {
    return row * 64 + (((chunk ^ ((row >> 1) & 3))) << 4);
}

// ---------------- geo features ----------------
__global__ void k_geo(const float* __restrict__ ab, const float* __restrict__ ob,
                      float* __restrict__ X) {
    int n = blockIdx.x * blockDim.x + threadIdx.x;
    if (n >= NTOT) return;
    const float* b = (n < NACT) ? &ab[n * 4] : &ob[(n - NACT) * 4];
    float x0 = b[0], y0 = b[1], x1 = b[2], y1 = b[3];
    float* o = &X[(size_t)n * DCOLS + 1024];
    o[0] = y1 - y0;
    o[1] = x1 - x0;
    o[2] = (x1 - x0) * 0.5f + x0;
    o[3] = (y1 - y0) * 0.5f + y0;
}

// ---------------- mean-pool 196 -> 1 ----------------
__global__ __launch_bounds__(256) void k_meanpool(const float* __restrict__ af,
                                                  float* __restrict__ X) {
    int w = blockIdx.x * 4 + (threadIdx.x >> 6);
    int lane = threadIdx.x & 63;
    const float* src = af + (size_t)w * 196;
    float s = src[lane] + src[lane + 64] + src[lane + 128];
    if (lane < 4) s += src[192 + lane];
    #pragma unroll
    for (int off = 32; off; off >>= 1) s += __shfl_down(s, off);
    if (lane == 0) {
        int n = w >> 10, c = w & 1023;
        X[(size_t)n * DCOLS + c] = s * (1.0f / 196.0f);
    }
}

// ---------------- pack adjacency into bitmask ----------------
__global__ __launch_bounds__(256) void k_packmask(const int* __restrict__ adj,
                                                  unsigned long long* __restrict__ mb) {
    int w = blockIdx.x * 4 + (threadIdx.x >> 6);
    int lane = threadIdx.x & 63;
    int v = adj[(size_t)w * 64 + lane];
    unsigned long long m = __ballot(v > 0);
    if (lane == 0) mb[w] = m;
}

// ---------------- transpose + convert weights: W[K][N] f32 -> Wt[Npad][Kpad] bf16 ----------------
__global__ __launch_bounds__(256) void k_transpW(const float* __restrict__ W, int K, int N,
                                                 short* __restrict__ Wt, int Kpad, int Npad) {
    __shared__ float Ws[32][33];
    int k0 = blockIdx.x * 32, n0 = blockIdx.y * 32;
    int t = threadIdx.x;
    #pragma unroll
    for (int i = 0; i < 4; ++i) {
        int j = t + i * 256;
        int r = j >> 5, c = j & 31;
        float v = 0.f;
        if (k0 + r < K && n0 + c < N) v = W[(size_t)(k0 + r) * N + n0 + c];
        Ws[r][c] = v;
    }
    __syncthreads();
    #pragma unroll
    for (int i = 0; i < 4; ++i) {
        int j = t + i * 256;
        int n = j >> 5, k = j & 31;
        Wt[(size_t)(n0 + n) * Kpad + k0 + k] = f2bf(Ws[k][n]);
    }
}

// ---------------- convert fp32 [4096][1028] -> bf16 [4096][1056] (zero pad) ----------------
__global__ __launch_bounds__(256) void k_convX(const float* __restrict__ X,
                                               short* __restrict__ Xb) {
    int i = blockIdx.x * 256 + threadIdx.x;      // 4096*132 total
    int n = i / 132, g = i % 132;
    int c0 = g * 8;
    short8v o;
    if (c0 + 8 <= DCOLS) {
        float4 v0 = *reinterpret_cast<const float4*>(&X[(size_t)n * DCOLS + c0]);
        float4 v1 = *reinterpret_cast<const float4*>(&X[(size_t)n * DCOLS + c0 + 4]);
        o[0]=f2bf(v0.x); o[1]=f2bf(v0.y); o[2]=f2bf(v0.z); o[3]=f2bf(v0.w);
        o[4]=f2bf(v1.x); o[5]=f2bf(v1.y); o[6]=f2bf(v1.z); o[7]=f2bf(v1.w);
    } else {
        #pragma unroll
        for (int j = 0; j < 8; ++j)
            o[j] = (c0 + j < DCOLS) ? f2bf(X[(size_t)n * DCOLS + c0 + j]) : (short)0;
    }
    *reinterpret_cast<short8v*>(&Xb[(size_t)n * KPAD + c0]) = o;
}

// ---------------- dense bf16 MFMA GEMM, 128x128x32, 4-wave quadrant ----------------
// MODE 0: obj   A=f32 global, epi: relu(acc+bias) -> f32 C
// MODE 1: wh    A=bf16 global, epi: bf16 C^T (WHT) + fused f1/f2 atomics
// MODE 3: fc    A=bf16 global, epi: acc+bias+resid -> f32 C
template <int MODE>
__global__ __launch_bounds__(256, 2) void k_mm(
    const void* __restrict__ Aptr, int lda,
    const short* __restrict__ Bt, int ldb,
    void* __restrict__ Cptr, int ldc,
    const float* __restrict__ bias,
    const float* __restrict__ resid, int ldr,
    float* __restrict__ F1, float* __restrict__ F2,
    const float* __restrict__ AV,
    int nk, int Nvalid) {
    __shared__ char sm[16384];                 // As: [128][32]bf16 @0, Bs: [128][32]bf16 @8192
    const int t = threadIdx.x;
    const int m0 = blockIdx.x * 128;
    const int n0 = blockIdx.y * 128;
    const int z = blockIdx.z;

    short* Cwh = nullptr;
    float* Cf  = nullptr;
    if constexpr (MODE == 1) {
        Bt += (size_t)z * (NPADH * KPAD);
        Cwh = (short*)Cptr + (size_t)z * ((size_t)NPADH * NTOT);
        AV += z * (2 * NHID_);
        F1 += z * NTOT; F2 += z * NTOT;
    } else {
        Cf = (float*)Cptr;
    }

    // staging indices: each thread loads one row's 32B (2 x short8v)
    const int ar = t >> 1, acp = t & 1;
    // mfma lane geometry
    const int wv = t >> 6, lane = t & 63, lr = lane & 15, lk = lane >> 4;
    const int wr = wv >> 1, wc = wv & 1;
    int aoff[4], boff[4];
    #pragma unroll
    for (int i = 0; i < 4; ++i) aoff[i] = swz(64 * wr + 16 * i + lr, lk);
    #pragma unroll
    for (int j = 0; j < 4; ++j) boff[j] = 8192 + swz(64 * wc + 16 * j + lr, lk);

    f32x4 acc[4][4];
    #pragma unroll
    for (int i = 0; i < 4; ++i)
        #pragma unroll
        for (int j = 0; j < 4; ++j) acc[i][j] = (f32x4){0.f, 0.f, 0.f, 0.f};

    for (int kt = 0; kt < nk; ++kt) {
        const int k0 = kt * 32;
        // ---- stage A ----
        if constexpr (MODE == 0) {
            const float* ap = (const float*)Aptr + (size_t)(m0 + ar) * lda + k0 + acp * 16;
            float4 u0 = *reinterpret_cast<const float4*>(ap);
            float4 u1 = *reinterpret_cast<const float4*>(ap + 4);
            float4 u2 = *reinterpret_cast<const float4*>(ap + 8);
            float4 u3 = *reinterpret_cast<const float4*>(ap + 12);
            short8v s0, s1;
            s0[0]=f2bf(u0.x); s0[1]=f2bf(u0.y); s0[2]=f2bf(u0.z); s0[3]=f2bf(u0.w);
            s0[4]=f2bf(u1.x); s0[5]=f2bf(u1.y); s0[6]=f2bf(u1.z); s0[7]=f2bf(u1.w);
            s1[0]=f2bf(u2.x); s1[1]=f2bf(u2.y); s1[2]=f2bf(u2.z); s1[3]=f2bf(u2.w);
            s1[4]=f2bf(u3.x); s1[5]=f2bf(u3.y); s1[6]=f2bf(u3.z); s1[7]=f2bf(u3.w);
            *reinterpret_cast<short8v*>(sm + swz(ar, 2 * acp)) = s0;
            *reinterpret_cast<short8v*>(sm + swz(ar, 2 * acp + 1)) = s1;
        } else {
            const short* ap = (const short*)Aptr + (size_t)(m0 + ar) * lda + k0 + acp * 16;
            short8v v0 = *reinterpret_cast<const short8v*>(ap);
            short8v v1 = *reinterpret_cast<const short8v*>(ap + 8);
            *reinterpret_cast<short8v*>(sm + swz(ar, 2 * acp)) = v0;
            *reinterpret_cast<short8v*>(sm + swz(ar, 2 * acp + 1)) = v1;
        }
        // ---- stage B ----
        {
            const short* bp = Bt + (size_t)(n0 + ar) * ldb + k0 + acp * 16;
            short8v v0 = *reinterpret_cast<const short8v*>(bp);
            short8v v1 = *reinterpret_cast<const short8v*>(bp + 8);
            *reinterpret_cast<short8v*>(sm + 8192 + swz(ar, 2 * acp)) = v0;
            *reinterpret_cast<short8v*>(sm + 8192 + swz(ar, 2 * acp + 1)) = v1;
        }
        __syncthreads();
        // ---- MFMA 4x4 ----
        short8v a[4], b[4];
        #pragma unroll
        for (int i = 0; i < 4; ++i) a[i] = *reinterpret_cast<short8v*>(sm + aoff[i]);
        #pragma unroll
        for (int j = 0; j < 4; ++j) b[j] = *reinterpret_cast<short8v*>(sm + boff[j]);
        #pragma unroll
        for (int i = 0; i < 4; ++i)
            #pragma unroll
            for (int j = 0; j < 4; ++j)
                acc[i][j] = __builtin_amdgcn_mfma_f32_16x16x32_bf16(a[i], b[j], acc[i][j], 0, 0, 0);
        __syncthreads();
    }

    // ---- epilogue ----
    const int mb0 = m0 + 64 * wr + 4 * lk;
    const int cb0 = n0 + 64 * wc + lr;
    if constexpr (MODE == 0 || MODE == 3) {
        #pragma unroll
        for (int i = 0; i < 4; ++i)
            #pragma unroll
            for (int j = 0; j < 4; ++j) {
                int c = cb0 + 16 * j;
                if (c < Nvalid) {
                    #pragma unroll
                    for (int rr = 0; rr < 4; ++rr) {
                        int m = mb0 + 16 * i + rr;
                        float v = acc[i][j][rr] + bias[c];
                        if constexpr (MODE == 0) v = fmaxf(v, 0.f);
                        if constexpr (MODE == 3) v += resid[(size_t)m * ldr + c];
                        Cf[(size_t)m * ldc + c] = v;
                    }
                }
            }
    } else {  // MODE 1: Wh -> WHT (d-major) + fused f1/f2
        float la1[4], la2[4];
        #pragma unroll
        for (int j = 0; j < 4; ++j) {
            int d = cb0 + 16 * j;
            la1[j] = (d < NHID_) ? AV[d] : 0.f;
            la2[j] = (d < NHID_) ? AV[NHID_ + d] : 0.f;
        }
        #pragma unroll
        for (int i = 0; i < 4; ++i) {
            #pragma unroll
            for (int j = 0; j < 4; ++j) {
                int d = cb0 + 16 * j;
                short4v o;
                o[0] = f2bf(acc[i][j][0]); o[1] = f2bf(acc[i][j][1]);
                o[2] = f2bf(acc[i][j][2]); o[3] = f2bf(acc[i][j][3]);
                *reinterpret_cast<short4v*>(&Cwh[(size_t)d * NTOT + mb0 + 16 * i]) = o;
            }
            #pragma unroll
            for (int rr = 0; rr < 4; ++rr) {
                float s1 = 0.f, s2 = 0.f;
                #pragma unroll
                for (int j = 0; j < 4; ++j) {
                    s1 += acc[i][j][rr] * la1[j];
                    s2 += acc[i][j][rr] * la2[j];
                }
                #pragma unroll
                for (int mk = 1; mk < 16; mk <<= 1) {
                    s1 += __shfl_xor(s1, mk);
                    s2 += __shfl_xor(s2, mk);
                }
                if (lr == 0) {
                    int m = mb0 + 16 * i + rr;
                    atomicAdd(&F1[m], s1);
                    atomicAdd(&F2[m], s2);
                }
            }
        }
    }
}

// ---------------- fused PV: one block = 64 rows x full padded head (384 cols) ----------------
// P generated once per (n,m); grid (64, 1, 4)
__global__ __launch_bounds__(256, 1) void k_pv(
    const short* __restrict__ WHT,
    const float* __restrict__ F1, const float* __restrict__ F2,
    const float* __restrict__ RMAX, const float* __restrict__ RDEN,
    const unsigned long long* __restrict__ MB,
    short* __restrict__ Gb) {
    __shared__ char sm[28672];                 // Ps: [64][32] @0 (4KB), Vs: [384][32] @4096 (24KB)
    const int t = threadIdx.x;
    const int m0 = blockIdx.x * 64;
    const int h = blockIdx.z;
    const short* WhH = WHT + (size_t)h * ((size_t)NPADH * NTOT);
    const float* F1h = F1 + h * NTOT;
    const float* F2h = F2 + h * NTOT;
    const int gcol = h * NHID_;

    // P-gen: thread handles row pr = t>>2, 8 m-values at quarter pq
    const int pr = t >> 2, pq = t & 3;
    const int n = m0 + pr;
    const float f1n = F1h[n];
    const float rmx = RMAX[h * NTOT + n];
    const float psc = 1.0f / RDEN[h * NTOT + n];
    const unsigned long long* mrow = MB + (size_t)n * 64;

    // V staging: thread loads 3 rows x 32B
    const int vr = t >> 1, vcp = t & 1;

    // mfma lane geometry: wave wv owns all 64 rows x cols [96*wv, 96*wv+96)
    const int wv = t >> 6, lane = t & 63, lr = lane & 15, lk = lane >> 4;
    int aoff[4], boff[6];
    #pragma unroll
    for (int i = 0; i < 4; ++i) aoff[i] = swz(16 * i + lr, lk);
    #pragma unroll
    for (int j = 0; j < 6; ++j) boff[j] = 4096 + swz(96 * wv + 16 * j + lr, lk);

    f32x4 acc[4][6];
    #pragma unroll
    for (int i = 0; i < 4; ++i)
        #pragma unroll
        for (int j = 0; j < 6; ++j) acc[i][j] = (f32x4){0.f, 0.f, 0.f, 0.f};

    for (int kt = 0; kt < NTOT / 32; ++kt) {
        const int k0 = kt * 32;
        // ---- generate P tile [64][32] ----
        {
            const int mk = k0 + pq * 8;
            unsigned long long wbits = mrow[k0 >> 6] >> ((k0 & 63) + pq * 8);
            float4 q0 = *reinterpret_cast<const float4*>(F2h + mk);
            float4 q1 = *reinterpret_cast<const float4*>(F2h + mk + 4);
            float fv[8] = {q0.x, q0.y, q0.z, q0.w, q1.x, q1.y, q1.z, q1.w};
            short8v o;
            #pragma unroll
            for (int j = 0; j < 8; ++j) {
                float e = f1n + fv[j];
                e = e > 0.f ? e : 0.2f * e;
                float p = ((wbits >> j) & 1ULL) ? __expf(e - rmx) * psc : 0.f;
                o[j] = f2bf(p);
            }
            *reinterpret_cast<short8v*>(sm + swz(pr, pq)) = o;
        }
        // ---- stage V tile [384][32] ----
        #pragma unroll
        for (int rep = 0; rep < 3; ++rep) {
            int row = vr + rep * 128;
            const short* vp = WhH + (size_t)row * NTOT + k0 + vcp * 16;
            short8v v0 = *reinterpret_cast<const short8v*>(vp);
            short8v v1 = *reinterpret_cast<const short8v*>(vp + 8);
            *reinterpret_cast<short8v*>(sm + 4096 + swz(row, 2 * vcp)) = v0;
            *reinterpret_cast<short8v*>(sm + 4096 + swz(row, 2 * vcp + 1)) = v1;
        }
        __syncthreads();
        // ---- MFMA 4x6 ----
        short8v a[4], b[6];
        #pragma unroll
        for (int i = 0; i < 4; ++i) a[i] = *reinterpret_cast<short8v*>(sm + aoff[i]);
        #pragma unroll
        for (int j = 0; j < 6; ++j) b[j] = *reinterpret_cast<short8v*>(sm + boff[j]);
        #pragma unroll
        for (int i = 0; i < 4; ++i)
            #pragma unroll
            for (int j = 0; j < 6; ++j)
                acc[i][j] = __builtin_amdgcn_mfma_f32_16x16x32_bf16(a[i], b[j], acc[i][j], 0, 0, 0);
        __syncthreads();
    }

    // ---- epilogue: elu -> bf16 Gb ----
    #pragma unroll
    for (int j = 0; j < 6; ++j) {
        int d = 96 * wv + 16 * j + lr;
        if (d < NHID_) {
            #pragma unroll
            for (int i = 0; i < 4; ++i)
                #pragma unroll
                for (int rr = 0; rr < 4; ++rr) {
                    int m = m0 + 16 * i + 4 * lk + rr;
                    float v = acc[i][j][rr];
                    v = v > 0.f ? v : expm1f(v);
                    Gb[(size_t)m * KPAD + gcol + d] = f2bf(v);
                }
        }
    }
}

// ---------------- per-row softmax stats (max, denom), online ----------------
__global__ __launch_bounds__(256) void k_rowstat(const float* __restrict__ F1,
                                                 const float* __restrict__ F2,
                                                 const unsigned long long* __restrict__ mb,
                                                 float* __restrict__ RMAX, float* __restrict__ RDEN) {
    __shared__ float f2s[NTOT];
    __shared__ unsigned long long mw[4][64];
    int h = blockIdx.y;
    const float4* src = reinterpret_cast<const float4*>(F2 + (size_t)h * NTOT);
    float4* dst = reinterpret_cast<float4*>(f2s);
    for (int i = threadIdx.x; i < NTOT / 4; i += 256) dst[i] = src[i];
    int wv = threadIdx.x >> 6, lane = threadIdx.x & 63;
    int n = blockIdx.x * 4 + wv;
    mw[wv][lane] = mb[(size_t)n * 64 + lane];
    __syncthreads();
    float f1n = F1[(size_t)h * NTOT + n];
    float rm = -1e30f, rs = 0.f;
    for (int b = 0; b < 64; ++b) {
        unsigned long long wb = mw[wv][b];
        if ((wb >> lane) & 1ULL) {
            float e = f1n + f2s[b * 64 + lane];
            e = e > 0.f ? e : 0.2f * e;
            if (e > rm) { rs *= __expf(rm - e); rm = e; }
            rs += __expf(e - rm);
        }
    }
    #pragma unroll
    for (int off = 32; off; off >>= 1) {
        float m2 = __shfl_down(rm, off), s2 = __shfl_down(rs, off);
        float nm = fmaxf(rm, m2);
        rs = rs * __expf(rm - nm) + s2 * __expf(m2 - nm);
        rm = nm;
    }
    if (lane == 0) {
        if (rs == 0.f) rs = 1.f;
        RMAX[(size_t)h * NTOT + n] = rm;
        RDEN[(size_t)h * NTOT + n] = rs;
    }
}

// ---------------- LayerNorm (in-place safe) ----------------
__global__ __launch_bounds__(256) void k_ln(const float* __restrict__ T,
                                            const float* __restrict__ g,
                                            const float* __restrict__ b,
                                            float* __restrict__ O) {
    int n = blockIdx.x;
    const float* row = T + (size_t)n * DCOLS;
    float s = 0.f, q = 0.f;
    for (int i = threadIdx.x; i < DCOLS / 4; i += 256) {
        float4 v = *reinterpret_cast<const float4*>(&row[i * 4]);
        s += v.x + v.y + v.z + v.w;
        q += v.x * v.x + v.y * v.y + v.z * v.z + v.w * v.w;
    }
    __shared__ float ls[2][4];
    int lane = threadIdx.x & 63, wv = threadIdx.x >> 6;
    #pragma unroll
    for (int off = 32; off; off >>= 1) {
        s += __shfl_down(s, off);
        q += __shfl_down(q, off);
    }
    if (lane == 0) { ls[0][wv] = s; ls[1][wv] = q; }
    __syncthreads();
    s = ls[0][0] + ls[0][1] + ls[0][2] + ls[0][3];
    q = ls[1][0] + ls[1][1] + ls[1][2] + ls[1][3];
    float mean = s * (1.0f / DCOLS);
    float var = q * (1.0f / DCOLS) - mean * mean;
    float rstd = rsqrtf(var + 1e-5f);
    float* orow = O + (size_t)n * DCOLS;
    for (int i = threadIdx.x; i < DCOLS; i += 256)
        orow[i] = (row[i] - mean) * rstd * g[i] + b[i];
}

// ---------------- logits + sigmoid + per-row loss partial ----------------
__global__ __launch_bounds__(128) void k_logits(const float* __restrict__ X,
                                                const float* __restrict__ W,
                                                const float* __restrict__ bias,
                                                const float* __restrict__ Y,
                                                float* __restrict__ out,
                                                float* __restrict__ lossp) {
    __shared__ float xs[DCOLS];
    int n = blockIdx.x;
    for (int i = threadIdx.x; i < DCOLS / 4; i += 128)
        *reinterpret_cast<float4*>(&xs[i * 4]) =
            *reinterpret_cast<const float4*>(&X[(size_t)n * DCOLS + i * 4]);
    __syncthreads();
    float loss = 0.f;
    int c = threadIdx.x;
    if (c < 80) {
        float acc = bias[c];
        for (int k = 0; k < DCOLS; ++k) acc += xs[k] * W[k * 80 + c];
        out[n * 80 + c] = 1.0f / (1.0f + expf(-acc));
        float y = Y[n * 80 + c];
        loss = fmaxf(acc, 0.f) - acc * y + log1pf(expf(-fabsf(acc)));
    }
    __shared__ float lr[2];
    int lane = threadIdx.x & 63, wv = threadIdx.x >> 6;
    #pragma unroll
    for (int off = 32; off; off >>= 1) loss += __shfl_down(loss, off);
    if (lane == 0) lr[wv] = loss;
    __syncthreads();
    if (threadIdx.x == 0) lossp[n] = lr[0] + lr[1];
}

__global__ __launch_bounds__(256) void k_lossfin(const float* __restrict__ lossp,
                                                 float* __restrict__ out) {
    float s = 0.f;
    for (int i = threadIdx.x; i < NACT; i += 256) s += lossp[i];
    #pragma unroll
    for (int off = 32; off; off >>= 1) s += __shfl_down(s, off);
    __shared__ float lr[4];
    int lane = threadIdx.x & 63, wv = threadIdx.x >> 6;
    if (lane == 0) lr[wv] = s;
    __syncthreads();
    if (threadIdx.x == 0) out[NACT * 80] = (lr[0] + lr[1] + lr[2] + lr[3]) / (float)(NACT * 80);
}

// ---------------- host launcher ----------------
extern "C" void kernel_launch(void* const* d_in, const int* in_sizes, int n_in,
                              void* d_out, int out_size, void* d_ws, size_t ws_size,
                              hipStream_t stream) {
    const float* actors_features  = (const float*)d_in[0];
    const float* actors_labels    = (const float*)d_in[1];
    const float* actors_boxes     = (const float*)d_in[2];
    const float* objects_features = (const float*)d_in[3];
    const float* objects_boxes    = (const float*)d_in[4];
    const int*   adj              = (const int*)d_in[5];
    const float* obj_W    = (const float*)d_in[6];
    const float* obj_b    = (const float*)d_in[7];
    const float* gatW[2]  = {(const float*)d_in[8],  (const float*)d_in[14]};
    const float* gatA[2]  = {(const float*)d_in[9],  (const float*)d_in[15]};
    const float* fcW[2]   = {(const float*)d_in[10], (const float*)d_in[16]};
    const float* fcB[2]   = {(const float*)d_in[11], (const float*)d_in[17]};
    const float* lnG[2]   = {(const float*)d_in[12], (const float*)d_in[18]};
    const float* lnB[2]   = {(const float*)d_in[13], (const float*)d_in[19]};
    const float* logits_W = (const float*)d_in[20];
    const float* logits_b = (const float*)d_in[21];
    float* out = (float*)d_out;

    float* ws   = (float*)d_ws;
    float* X0   = ws + OFF_X0;
    float* T    = ws + OFF_T;
    float* F1   = ws + OFF_F1;
    float* F2   = ws + OFF_F2;
    float* RMAX = ws + OFF_RMAX;
    float* RDEN = ws + OFF_RDEN;
    float* LOSSP= ws + OFF_LOSSP;
    unsigned long long* MASK = (unsigned long long*)(ws + OFF_MASK);
    short* Xb    = (short*)(ws + OFF_XB);
    short* Gb    = (short*)(ws + OFF_GB);
    short* objWt = (short*)(ws + OFF_OBJWT);
    short* gatWt = (short*)(ws + OFF_GATWT);
    short* fcWt  = (short*)(ws + OFF_FCWT);
    short* WHT   = (short*)(ws + OFF_WHT);

    hipMemsetAsync(F1, 0, 2 * 4 * NTOT * sizeof(float), stream);       // F1+F2
    hipMemsetAsync(Gb, 0, (size_t)NTOT * KPAD * 2, stream);

    k_geo<<<(NTOT + 255) / 256, 256, 0, stream>>>(actors_boxes, objects_boxes, X0);
    k_meanpool<<<(NACT * 1024) / 4, 256, 0, stream>>>(actors_features, X0);
    k_packmask<<<(NTOT * 64) / 4, 256, 0, stream>>>(adj, MASK);

    // weight transposes (bf16, padded)
    k_transpW<<<dim3(64, 32), 256, 0, stream>>>(obj_W, OFSZ, 1024, objWt, OFSZ, 1024);
    for (int L = 0; L < 2; ++L) {
        for (int h = 0; h < 4; ++h)
            k_transpW<<<dim3(33, 12), 256, 0, stream>>>(
                gatW[L] + (size_t)h * DCOLS * NHID_, DCOLS, NHID_,
                gatWt + (size_t)(L * 4 + h) * NPADH * KPAD, KPAD, NPADH);
        k_transpW<<<dim3(33, 36), 256, 0, stream>>>(
            fcW[L], DCOLS, DCOLS, fcWt + (size_t)L * NPADFC * KPAD, KPAD, NPADFC);
    }

    // objects reducer: relu(of @ obj_W + b) -> X0 rows [512,4096) cols [0,1024)
    k_mm<0><<<dim3(NOBJ / 128, 1024 / 128, 1), 256, 0, stream>>>(
        objects_features, OFSZ, objWt, OFSZ, X0 + (size_t)NACT * DCOLS, DCOLS,
        obj_b, nullptr, 0, nullptr, nullptr, nullptr,
        OFSZ / 32, 1024);

    k_convX<<<(NTOT * 132) / 256, 256, 0, stream>>>(X0, Xb);

    const float* xin = X0;
    for (int L = 0; L < 2; ++L) {
        if (L == 1) {
            hipMemsetAsync(F1, 0, 2 * 4 * NTOT * sizeof(float), stream);
            k_convX<<<(NTOT * 132) / 256, 256, 0, stream>>>(T, Xb);
        }
        // Wh GEMM + fused f1/f2
        k_mm<1><<<dim3(NTOT / 128, NPADH / 128, 4), 256, 0, stream>>>(
            Xb, KPAD, gatWt + (size_t)L * 4 * NPADH * KPAD, KPAD, WHT, 0,
            nullptr, nullptr, 0, F1, F2, gatA[L],
            KPAD / 32, NHID_);
        k_rowstat<<<dim3(NTOT / 4, 4), 256, 0, stream>>>(F1, F2, MASK, RMAX, RDEN);
        // fused PV
        k_pv<<<dim3(NTOT / 64, 1, 4), 256, 0, stream>>>(
            WHT, F1, F2, RMAX, RDEN, MASK, Gb);
        // fc + bias + resid
        k_mm<3><<<dim3(NTOT / 128, NPADFC / 128, 1), 256, 0, stream>>>(
            Gb, KPAD, fcWt + (size_t)L * NPADFC * KPAD, KPAD, T, DCOLS,
            fcB[L], xin, DCOLS, nullptr, nullptr, nullptr,
            KPAD / 32, DCOLS);
        k_ln<<<NTOT, 256, 0, stream>>>(T, lnG[L], lnB[L], T);
        xin = T;
    }
    k_logits<<<NACT, 128, 0, stream>>>(T, logits_W, logits_b, actors_labels, out, LOSSP);
    k_lossfin<<<1, 256, 0, stream>>>(LOSSP, out);
}

// Round 5
// 1431.641 us; speedup vs baseline: 2.8702x; 1.0883x over previous
//
#include <hip/hip_runtime.h>
#include <cstdint>

#define NACT 512
#define NOBJ 3584
#define NTOT 4096
#define DCOLS 1028
#define NHID_ 257
#define OFSZ 2048
#define KPAD 1056          // padded D for bf16 GEMM K
#define NPADH 320          // padded per-head hidden (5 x 64)
#define NWH   1280         // 4 heads x 320 stacked along N
#define NPADFC 1152        // padded fc out cols (9 x 128)

typedef float f32x4 __attribute__((ext_vector_type(4)));
typedef short short8v __attribute__((ext_vector_type(8)));
typedef short short4v __attribute__((ext_vector_type(4)));

// ---- workspace layout (float offsets; all 16B aligned) ----
static const size_t OFF_X0    = 0;                                   // 4096x1028 f32
static const size_t OFF_T     = 4210688;                             // 4096x1028 f32
static const size_t OFF_F1    = 8421376;                             // 4x4096 f32
static const size_t OFF_F2    = 8437760;
static const size_t OFF_RMAX  = 8454144;
static const size_t OFF_RDEN  = 8470528;
static const size_t OFF_LOSSP = 8486912;                             // 512
static const size_t OFF_MASK  = 8487424;                             // 4096x64 u64 = 524288 f
static const size_t OFF_XB    = 9011712;                             // 4096x1056 bf16
static const size_t OFF_GB    = 11174400;                            // 4096x1056 bf16
static const size_t OFF_OFB   = 13337088;                            // 3584x2048 bf16
static const size_t OFF_OBJWT = 17007104;                            // 1024x2048 bf16
static const size_t OFF_GATWT = 18055680;                            // 2 x 1280x1056 bf16
static const size_t OFF_FCWT  = 19407360;                            // 2 x 1152x1056 bf16
static const size_t OFF_WHT   = 20623872;                            // 4 x 320x4096 bf16 (ends 23245312 f)

__device__ __forceinline__ short f2bf(float x) {
    unsigned u = __float_as_uint(x);
    u += 0x7fffu + ((u >> 16) & 1u);
    return (short)(u >> 16);
}
// byte offset inside a [rows][32 bf16] LDS tile, XOR-swizzled 16B chunks.
// read chunk c of row r at: r*64 + ((c ^ ((r>>1)&3))<<4)  (max 2-way bank alias)
__device__ __forceinline__ int swz(int row, int chunk) {
    return row * 64 + (((chunk ^ ((row >> 1) & 3))) << 4);
}
// async global->LDS 16B: LDS dest is wave-uniform base + lane*16 (linear);
// swizzle achieved by pre-swizzling the per-lane GLOBAL source address.
__device__ __forceinline__ void gload16(const void* g, void* l) {
    __builtin_amdgcn_global_load_lds(
        (const __attribute__((address_space(1))) unsigned int*)g,
        (__attribute__((address_space(3))) unsigned int*)l, 16, 0, 0);
}

// ---------------- geo features (f32 + bf16) ----------------
__global__ void k_geo(const float* __restrict__ ab, const float* __restrict__ ob,
                      float* __restrict__ X, short* __restrict__ Xb) {
    int n = blockIdx.x * blockDim.x + threadIdx.x;
    if (n >= NTOT) return;
    const float* b = (n < NACT) ? &ab[n * 4] : &ob[(n - NACT) * 4];
    float x0 = b[0], y0 = b[1], x1 = b[2], y1 = b[3];
    float g0 = y1 - y0, g1 = x1 - x0;
    float g2 = (x1 - x0) * 0.5f + x0, g3 = (y1 - y0) * 0.5f + y0;
    float* o = &X[(size_t)n * DCOLS + 1024];
    o[0] = g0; o[1] = g1; o[2] = g2; o[3] = g3;
    short* ob2 = &Xb[(size_t)n * KPAD + 1024];
    ob2[0] = f2bf(g0); ob2[1] = f2bf(g1); ob2[2] = f2bf(g2); ob2[3] = f2bf(g3);
}

// ---------------- mean-pool 196 -> 1 (f32 + bf16) ----------------
__global__ __launch_bounds__(256) void k_meanpool(const float* __restrict__ af,
                                                  float* __restrict__ X,
                                                  short* __restrict__ Xb) {
    int w = blockIdx.x * 4 + (threadIdx.x >> 6);
    int lane = threadIdx.x & 63;
    const float* src = af + (size_t)w * 196;
    float s = src[lane] + src[lane + 64] + src[lane + 128];
    if (lane < 4) s += src[192 + lane];
    #pragma unroll
    for (int off = 32; off; off >>= 1) s += __shfl_down(s, off);
    if (lane == 0) {
        int n = w >> 10, c = w & 1023;
        float v = s * (1.0f / 196.0f);
        X[(size_t)n * DCOLS + c] = v;
        Xb[(size_t)n * KPAD + c] = f2bf(v);
    }
}

// ---------------- pack adjacency into bitmask ----------------
__global__ __launch_bounds__(256) void k_packmask(const int* __restrict__ adj,
                                                  unsigned long long* __restrict__ mb) {
    int w = blockIdx.x * 4 + (threadIdx.x >> 6);
    int lane = threadIdx.x & 63;
    int v = adj[(size_t)w * 64 + lane];
    unsigned long long m = __ballot(v > 0);
    if (lane == 0) mb[w] = m;
}

// ---------------- f32 -> bf16 bulk convert (n8 = elems/8) ----------------
__global__ __launch_bounds__(256) void k_convF(const float* __restrict__ src,
                                               short* __restrict__ dst, int n8) {
    int i = blockIdx.x * 256 + threadIdx.x;
    if (i >= n8) return;
    float4 a = *reinterpret_cast<const float4*>(src + (size_t)i * 8);
    float4 b = *reinterpret_cast<const float4*>(src + (size_t)i * 8 + 4);
    short8v o;
    o[0]=f2bf(a.x); o[1]=f2bf(a.y); o[2]=f2bf(a.z); o[3]=f2bf(a.w);
    o[4]=f2bf(b.x); o[5]=f2bf(b.y); o[6]=f2bf(b.z); o[7]=f2bf(b.w);
    *reinterpret_cast<short8v*>(dst + (size_t)i * 8) = o;
}

// ---------------- transpose + convert weights: W[K][N] f32 -> Wt[Npad][Kpad] bf16 ----------------
__global__ __launch_bounds__(256) void k_transpW(const float* __restrict__ W, int K, int N,
                                                 short* __restrict__ Wt, int Kpad) {
    __shared__ float Ws[32][33];
    int k0 = blockIdx.x * 32, n0 = blockIdx.y * 32;
    int t = threadIdx.x;
    #pragma unroll
    for (int i = 0; i < 4; ++i) {
        int j = t + i * 256;
        int r = j >> 5, c = j & 31;
        float v = 0.f;
        if (k0 + r < K && n0 + c < N) v = W[(size_t)(k0 + r) * N + n0 + c];
        Ws[r][c] = v;
    }
    __syncthreads();
    #pragma unroll
    for (int i = 0; i < 4; ++i) {
        int j = t + i * 256;
        int n = j >> 5, k = j & 31;
        Wt[(size_t)(n0 + n) * Kpad + k0 + k] = f2bf(Ws[k][n]);
    }
}

// ---------------- dense bf16 MFMA GEMM, 128x128x32, 4-wave quadrant, dbuf+gload_lds ----------------
// MODE 0: obj  epi: relu(acc+bias) -> f32 C + bf16 Cbf
// MODE 1: wh   epi: bf16 WHT[h][d][m] + fused f1/f2 atomics (N = 4 heads x 320)
// MODE 3: fc   epi: acc+bias+resid -> f32 C
template <int MODE>
__global__ __launch_bounds__(256, 2) void k_mm(
    const short* __restrict__ Ab, int lda,
    const short* __restrict__ Bt, int ldb,
    void* __restrict__ Cptr, int ldc,
    const float* __restrict__ bias,
    const float* __restrict__ resid, int ldr,
    float* __restrict__ F1, float* __restrict__ F2,
    const float* __restrict__ AV,
    short* __restrict__ Cbf,
    int nk, int Nvalid) {
    __shared__ char sm[32768];                 // 2 bufs x (A [128][64B] @0 + B [128][64B] @8192)
    const int t = threadIdx.x;
    const int m0 = blockIdx.x * 128;
    const int n0 = blockIdx.y * 128;
    const int wv = t >> 6, lane = t & 63, lr = lane & 15, lk = lane >> 4;
    const int wr = wv >> 1, wc = wv & 1;

    int aoff[4], boff[4];
    #pragma unroll
    for (int i = 0; i < 4; ++i) aoff[i] = swz(64 * wr + 16 * i + lr, lk);
    #pragma unroll
    for (int j = 0; j < 4; ++j) boff[j] = 8192 + swz(64 * wc + 16 * j + lr, lk);

    f32x4 acc[4][4];
    #pragma unroll
    for (int i = 0; i < 4; ++i)
        #pragma unroll
        for (int j = 0; j < 4; ++j) acc[i][j] = (f32x4){0.f, 0.f, 0.f, 0.f};

    // stage tile kt into buffer p: wave wv covers slots {2wv, 2wv+1} of A and B.
    // global chunk offset: 16B chunk = 8 shorts -> gch*8 (NOT gch*16: that was the R3 bug)
    auto stage = [&](int p, int k0) {
        char* base = sm + p * 16384;
        #pragma unroll
        for (int c = 0; c < 2; ++c) {
            int slot = 2 * wv + c;
            int row = slot * 16 + (lane >> 2);
            int gch = (lane & 3) ^ ((row >> 1) & 3);
            gload16(Ab + (size_t)(m0 + row) * lda + k0 + gch * 8, base + slot * 1024);
            gload16(Bt + (size_t)(n0 + row) * ldb + k0 + gch * 8, base + 8192 + slot * 1024);
        }
    };

    stage(0, 0);
    __syncthreads();
    int p = 0;
    for (int kt = 0; kt < nk; ++kt) {
        if (kt + 1 < nk) stage(p ^ 1, (kt + 1) * 32);
        const char* cb = sm + p * 16384;
        short8v a[4], b[4];
        #pragma unroll
        for (int i = 0; i < 4; ++i) a[i] = *reinterpret_cast<const short8v*>(cb + aoff[i]);
        #pragma unroll
        for (int j = 0; j < 4; ++j) b[j] = *reinterpret_cast<const short8v*>(cb + boff[j]);
        #pragma unroll
        for (int i = 0; i < 4; ++i)
            #pragma unroll
            for (int j = 0; j < 4; ++j)
                acc[i][j] = __builtin_amdgcn_mfma_f32_16x16x32_bf16(a[i], b[j], acc[i][j], 0, 0, 0);
        __syncthreads();                       // drains gloads (vmcnt) + ds reads
        p ^= 1;
    }

    // ---- epilogue ----
    const int mb0 = m0 + 64 * wr + 4 * lk;
    if constexpr (MODE == 0 || MODE == 3) {
        float* Cf = (float*)Cptr;
        #pragma unroll
        for (int i = 0; i < 4; ++i)
            #pragma unroll
            for (int j = 0; j < 4; ++j) {
                int c = n0 + 64 * wc + 16 * j + lr;
                if (c < Nvalid) {
                    #pragma unroll
                    for (int rr = 0; rr < 4; ++rr) {
                        int m = mb0 + 16 * i + rr;
                        float v = acc[i][j][rr] + bias[c];
                        if constexpr (MODE == 0) v = fmaxf(v, 0.0f);
                        if constexpr (MODE == 3) v += resid[(size_t)m * ldr + c];
                        Cf[(size_t)m * ldc + c] = v;
                        if constexpr (MODE == 0) Cbf[(size_t)m * KPAD + c] = f2bf(v);
                    }
                }
            }
    } else {  // MODE 1: WHT (d-major within head) + fused f1/f2
        const int cwbase = n0 + 64 * wc;       // 64-aligned; 64 | 320 -> head-uniform
        const int h = cwbase / NPADH;
        const int dwbase = cwbase - h * NPADH;
        const float* AVh = AV + h * (2 * NHID_);
        float* F1h = F1 + h * NTOT;
        float* F2h = F2 + h * NTOT;
        short* CwhH = (short*)Cptr + (size_t)h * ((size_t)NPADH * NTOT);
        float la1[4], la2[4];
        #pragma unroll
        for (int j = 0; j < 4; ++j) {
            int d = dwbase + 16 * j + lr;
            la1[j] = (d < NHID_) ? AVh[d] : 0.f;
            la2[j] = (d < NHID_) ? AVh[NHID_ + d] : 0.f;
        }
        #pragma unroll
        for (int i = 0; i < 4; ++i) {
            #pragma unroll
            for (int j = 0; j < 4; ++j) {
                int d = dwbase + 16 * j + lr;
                short4v o;
                o[0] = f2bf(acc[i][j][0]); o[1] = f2bf(acc[i][j][1]);
                o[2] = f2bf(acc[i][j][2]); o[3] = f2bf(acc[i][j][3]);
                *reinterpret_cast<short4v*>(&CwhH[(size_t)d * NTOT + mb0 + 16 * i]) = o;
            }
            #pragma unroll
            for (int rr = 0; rr < 4; ++rr) {
                float s1 = 0.f, s2 = 0.f;
                #pragma unroll
                for (int j = 0; j < 4; ++j) {
                    s1 += acc[i][j][rr] * la1[j];
                    s2 += acc[i][j][rr] * la2[j];
                }
                #pragma unroll
                for (int mk = 1; mk < 16; mk <<= 1) {
                    s1 += __shfl_xor(s1, mk);
                    s2 += __shfl_xor(s2, mk);
                }
                if (lr == 0) {
                    int m = mb0 + 16 * i + rr;
                    atomicAdd(&F1h[m], s1);
                    atomicAdd(&F2h[m], s2);
                }
            }
        }
    }
}

// ---------------- fused PV: 64 rows x full head (320 cols), XCD-pinned heads ----------------
// head h -> XCDs {2h, 2h+1} so each XCD's L2 caches one head's WHT (2.6MB < 4MB)
__global__ __launch_bounds__(256, 2) void k_pv(
    const short* __restrict__ WHT,
    const float* __restrict__ F1, const float* __restrict__ F2,
    const float* __restrict__ RMAX, const float* __restrict__ RDEN,
    const unsigned long long* __restrict__ MB,
    short* __restrict__ Gb) {
    __shared__ char sm[49152];                 // 2 bufs x (Ps [64][64B] @0 + Vs [320][64B] @4096)
    const int t = threadIdx.x;
    const int i0 = blockIdx.x;                 // 256 blocks
    const int xcd = i0 & 7, slot = i0 >> 3;
    const int h = xcd >> 1;
    const int m0 = (slot * 2 + (xcd & 1)) * 64;
    const short* WhH = WHT + (size_t)h * ((size_t)NPADH * NTOT);
    const float* F2h = F2 + h * NTOT;
    const int gcol = h * NHID_;

    // P-gen: thread -> row pr, 8 m-values at quarter pq
    const int pr = t >> 2, pq = t & 3;
    const int n = m0 + pr;
    const float f1n = F1[h * NTOT + n];
    const float rmx = RMAX[h * NTOT + n];
    const float psc = 1.0f / RDEN[h * NTOT + n];
    const unsigned long long* mrow = MB + (size_t)n * 64;

    const int wv = t >> 6, lane = t & 63, lr = lane & 15, lk = lane >> 4;
    int aoff[4], boff[5];
    #pragma unroll
    for (int i = 0; i < 4; ++i) aoff[i] = swz(16 * i + lr, lk);
    #pragma unroll
    for (int j = 0; j < 5; ++j) boff[j] = 4096 + swz(80 * wv + 16 * j + lr, lk);

    f32x4 acc[4][5];
    #pragma unroll
    for (int i = 0; i < 4; ++i)
        #pragma unroll
        for (int j = 0; j < 5; ++j) acc[i][j] = (f32x4){0.f, 0.f, 0.f, 0.f};

    auto stageV = [&](int p, int k0) {
        char* vb = sm + p * 24576 + 4096;
        #pragma unroll
        for (int c = 0; c < 5; ++c) {
            int slot2 = 5 * wv + c;
            int row = slot2 * 16 + (lane >> 2);
            int gch = (lane & 3) ^ ((row >> 1) & 3);
            gload16(WhH + (size_t)row * NTOT + k0 + gch * 8, vb + slot2 * 1024);
        }
    };
    auto pgen = [&](int p, int k0) {
        const int mk = k0 + pq * 8;
        unsigned long long wbits = mrow[k0 >> 6] >> ((k0 & 63) + pq * 8);
        float4 q0 = *reinterpret_cast<const float4*>(F2h + mk);
        float4 q1 = *reinterpret_cast<const float4*>(F2h + mk + 4);
        float fv[8] = {q0.x, q0.y, q0.z, q0.w, q1.x, q1.y, q1.z, q1.w};
        short8v o;
        #pragma unroll
        for (int j = 0; j < 8; ++j) {
            float e = f1n + fv[j];
            e = e > 0.f ? e : 0.2f * e;
            float pvv = ((wbits >> j) & 1ULL) ? __expf(e - rmx) * psc : 0.f;
            o[j] = f2bf(pvv);
        }
        *reinterpret_cast<short8v*>(sm + p * 24576 + swz(pr, pq)) = o;
    };

    stageV(0, 0);
    pgen(0, 0);
    __syncthreads();
    int p = 0;
    for (int kt = 0; kt < NTOT / 32; ++kt) {
        if (kt + 1 < NTOT / 32) {
            stageV(p ^ 1, (kt + 1) * 32);
            pgen(p ^ 1, (kt + 1) * 32);
        }
        const char* cb = sm + p * 24576;
        short8v a[4], b[5];
        #pragma unroll
        for (int i = 0; i < 4; ++i) a[i] = *reinterpret_cast<const short8v*>(cb + aoff[i]);
        #pragma unroll
        for (int j = 0; j < 5; ++j) b[j] = *reinterpret_cast<const short8v*>(cb + boff[j]);
        #pragma unroll
        for (int i = 0; i < 4; ++i)
            #pragma unroll
            for (int j = 0; j < 5; ++j)
                acc[i][j] = __builtin_amdgcn_mfma_f32_16x16x32_bf16(a[i], b[j], acc[i][j], 0, 0, 0);
        __syncthreads();
        p ^= 1;
    }

    // ---- epilogue: elu -> bf16 Gb ----
    #pragma unroll
    for (int j = 0; j < 5; ++j) {
        int d = 80 * wv + 16 * j + lr;
        if (d < NHID_) {
            #pragma unroll
            for (int i = 0; i < 4; ++i)
                #pragma unroll
                for (int rr = 0; rr < 4; ++rr) {
                    int m = m0 + 16 * i + 4 * lk + rr;
                    float v = acc[i][j][rr];
                    v = v > 0.f ? v : expm1f(v);
                    Gb[(size_t)m * KPAD + gcol + d] = f2bf(v);
                }
        }
    }
}

// ---------------- per-row softmax stats (max, denom), online ----------------
__global__ __launch_bounds__(256) void k_rowstat(const float* __restrict__ F1,
                                                 const float* __restrict__ F2,
                                                 const unsigned long long* __restrict__ mb,
                                                 float* __restrict__ RMAX, float* __restrict__ RDEN) {
    __shared__ float f2s[NTOT];
    __shared__ unsigned long long mw[4][64];
    int h = blockIdx.y;
    const float4* src = reinterpret_cast<const float4*>(F2 + (size_t)h * NTOT);
    float4* dst = reinterpret_cast<float4*>(f2s);
    for (int i = threadIdx.x; i < NTOT / 4; i += 256) dst[i] = src[i];
    int wv = threadIdx.x >> 6, lane = threadIdx.x & 63;
    int n = blockIdx.x * 4 + wv;
    mw[wv][lane] = mb[(size_t)n * 64 + lane];
    __syncthreads();
    float f1n = F1[(size_t)h * NTOT + n];
    float rm = -1e30f, rs = 0.f;
    for (int b = 0; b < 64; ++b) {
        unsigned long long wb = mw[wv][b];
        if ((wb >> lane) & 1ULL) {
            float e = f1n + f2s[b * 64 + lane];
            e = e > 0.f ? e : 0.2f * e;
            if (e > rm) { rs *= __expf(rm - e); rm = e; }
            rs += __expf(e - rm);
        }
    }
    #pragma unroll
    for (int off = 32; off; off >>= 1) {
        float m2 = __shfl_down(rm, off), s2 = __shfl_down(rs, off);
        float nm = fmaxf(rm, m2);
        rs = rs * __expf(rm - nm) + s2 * __expf(m2 - nm);
        rm = nm;
    }
    if (lane == 0) {
        if (rs == 0.f) rs = 1.f;
        RMAX[(size_t)h * NTOT + n] = rm;
        RDEN[(size_t)h * NTOT + n] = rs;
    }
}

// ---------------- LayerNorm (in-place safe, optional bf16 out) ----------------
__global__ __launch_bounds__(256) void k_ln(const float* __restrict__ T,
                                            const float* __restrict__ g,
                                            const float* __restrict__ b,
                                            float* __restrict__ O,
                                            short* __restrict__ xb) {
    int n = blockIdx.x;
    const float* row = T + (size_t)n * DCOLS;
    float s = 0.f, q = 0.f;
    for (int i = threadIdx.x; i < DCOLS / 4; i += 256) {
        float4 v = *reinterpret_cast<const float4*>(&row[i * 4]);
        s += v.x + v.y + v.z + v.w;
        q += v.x * v.x + v.y * v.y + v.z * v.z + v.w * v.w;
    }
    __shared__ float ls[2][4];
    int lane = threadIdx.x & 63, wv = threadIdx.x >> 6;
    #pragma unroll
    for (int off = 32; off; off >>= 1) {
        s += __shfl_down(s, off);
        q += __shfl_down(q, off);
    }
    if (lane == 0) { ls[0][wv] = s; ls[1][wv] = q; }
    __syncthreads();
    s = ls[0][0] + ls[0][1] + ls[0][2] + ls[0][3];
    q = ls[1][0] + ls[1][1] + ls[1][2] + ls[1][3];
    float mean = s * (1.0f / DCOLS);
    float var = q * (1.0f / DCOLS) - mean * mean;
    float rstd = rsqrtf(var + 1e-5f);
    float* orow = O + (size_t)n * DCOLS;
    for (int i = threadIdx.x; i < DCOLS; i += 256) {
        float v = (row[i] - mean) * rstd * g[i] + b[i];
        orow[i] = v;
        if (xb) xb[(size_t)n * KPAD + i] = f2bf(v);
    }
}

// ---------------- logits + sigmoid + per-row loss partial ----------------
__global__ __launch_bounds__(128) void k_logits(const float* __restrict__ X,
                                                const float* __restrict__ W,
                                                const float* __restrict__ bias,
                                                const float* __restrict__ Y,
                                                float* __restrict__ out,
                                                float* __restrict__ lossp) {
    __shared__ float xs[DCOLS];
    int n = blockIdx.x;
    for (int i = threadIdx.x; i < DCOLS / 4; i += 128)
        *reinterpret_cast<float4*>(&xs[i * 4]) =
            *reinterpret_cast<const float4*>(&X[(size_t)n * DCOLS + i * 4]);
    __syncthreads();
    float loss = 0.f;
    int c = threadIdx.x;
    if (c < 80) {
        float acc = bias[c];
        for (int k = 0; k < DCOLS; ++k) acc += xs[k] * W[k * 80 + c];
        out[n * 80 + c] = 1.0f / (1.0f + expf(-acc));
        float y = Y[n * 80 + c];
        loss = fmaxf(acc, 0.f) - acc * y + log1pf(expf(-fabsf(acc)));
    }
    __shared__ float lr[2];
    int lane = threadIdx.x & 63, wv = threadIdx.x >> 6;
    #pragma unroll
    for (int off = 32; off; off >>= 1) loss += __shfl_down(loss, off);
    if (lane == 0) lr[wv] = loss;
    __syncthreads();
    if (threadIdx.x == 0) lossp[n] = lr[0] + lr[1];
}

__global__ __launch_bounds__(256) void k_lossfin(const float* __restrict__ lossp,
                                                 float* __restrict__ out) {
    float s = 0.f;
    for (int i = threadIdx.x; i < NACT; i += 256) s += lossp[i];
    #pragma unroll
    for (int off = 32; off; off >>= 1) s += __shfl_down(s, off);
    __shared__ float lr[4];
    int lane = threadIdx.x & 63, wv = threadIdx.x >> 6;
    if (lane == 0) lr[wv] = s;
    __syncthreads();
    if (threadIdx.x == 0) out[NACT * 80] = (lr[0] + lr[1] + lr[2] + lr[3]) / (float)(NACT * 80);
}

// ---------------- host launcher ----------------
extern "C" void kernel_launch(void* const* d_in, const int* in_sizes, int n_in,
                              void* d_out, int out_size, void* d_ws, size_t ws_size,
                              hipStream_t stream) {
    const float* actors_features  = (const float*)d_in[0];
    const float* actors_labels    = (const float*)d_in[1];
    const float* actors_boxes     = (const float*)d_in[2];
    const float* objects_features = (const float*)d_in[3];
    const float* objects_boxes    = (const float*)d_in[4];
    const int*   adj              = (const int*)d_in[5];
    const float* obj_W    = (const float*)d_in[6];
    const float* obj_b    = (const float*)d_in[7];
    const float* gatW[2]  = {(const float*)d_in[8],  (const float*)d_in[14]};
    const float* gatA[2]  = {(const float*)d_in[9],  (const float*)d_in[15]};
    const float* fcW[2]   = {(const float*)d_in[10], (const float*)d_in[16]};
    const float* fcB[2]   = {(const float*)d_in[11], (const float*)d_in[17]};
    const float* lnG[2]   = {(const float*)d_in[12], (const float*)d_in[18]};
    const float* lnB[2]   = {(const float*)d_in[13], (const float*)d_in[19]};
    const float* logits_W = (const float*)d_in[20];
    const float* logits_b = (const float*)d_in[21];
    float* out = (float*)d_out;

    float* ws   = (float*)d_ws;
    float* X0   = ws + OFF_X0;
    float* T    = ws + OFF_T;
    float* F1   = ws + OFF_F1;
    float* F2   = ws + OFF_F2;
    float* RMAX = ws + OFF_RMAX;
    float* RDEN = ws + OFF_RDEN;
    float* LOSSP= ws + OFF_LOSSP;
    unsigned long long* MASK = (unsigned long long*)(ws + OFF_MASK);
    short* Xb    = (short*)(ws + OFF_XB);
    short* Gb    = (short*)(ws + OFF_GB);
    short* OFb   = (short*)(ws + OFF_OFB);
    short* objWt = (short*)(ws + OFF_OBJWT);
    short* gatWt = (short*)(ws + OFF_GATWT);
    short* fcWt  = (short*)(ws + OFF_FCWT);
    short* WHT   = (short*)(ws + OFF_WHT);

    hipMemsetAsync(F1, 0, 2 * 4 * NTOT * sizeof(float), stream);           // F1+F2
    hipMemsetAsync(Gb, 0, (size_t)NTOT * KPAD * 2, stream);                // pad cols must be 0
    hipMemsetAsync(Xb, 0, (size_t)NTOT * KPAD * 2, stream);                // pad cols must be 0

    k_geo<<<(NTOT + 255) / 256, 256, 0, stream>>>(actors_boxes, objects_boxes, X0, Xb);
    k_meanpool<<<(NACT * 1024) / 4, 256, 0, stream>>>(actors_features, X0, Xb);
    k_packmask<<<(NTOT * 64) / 4, 256, 0, stream>>>(adj, MASK);
    k_convF<<<(NOBJ * OFSZ / 8 + 255) / 256, 256, 0, stream>>>(objects_features, OFb, NOBJ * OFSZ / 8);

    // weight transposes (bf16, padded)
    k_transpW<<<dim3(64, 32), 256, 0, stream>>>(obj_W, OFSZ, 1024, objWt, OFSZ);
    for (int L = 0; L < 2; ++L) {
        for (int h = 0; h < 4; ++h)
            k_transpW<<<dim3(33, 10), 256, 0, stream>>>(
                gatW[L] + (size_t)h * DCOLS * NHID_, DCOLS, NHID_,
                gatWt + (size_t)L * NWH * KPAD + (size_t)h * NPADH * KPAD, KPAD);
        k_transpW<<<dim3(33, 36), 256, 0, stream>>>(
            fcW[L], DCOLS, DCOLS, fcWt + (size_t)L * NPADFC * KPAD, KPAD);
    }

    // objects reducer: relu(of @ obj_W + b) -> X0 rows [512,4096) + Xb bf16
    k_mm<0><<<dim3(NOBJ / 128, 1024 / 128), 256, 0, stream>>>(
        OFb, OFSZ, objWt, OFSZ, X0 + (size_t)NACT * DCOLS, DCOLS,
        obj_b, nullptr, 0, nullptr, nullptr, nullptr,
        Xb + (size_t)NACT * KPAD, OFSZ / 32, 1024);

    const float* xin = X0;
    for (int L = 0; L < 2; ++L) {
        if (L == 1)
            hipMemsetAsync(F1, 0, 2 * 4 * NTOT * sizeof(float), stream);
        // Wh GEMM (all heads, N=1280) + fused f1/f2
        k_mm<1><<<dim3(NTOT / 128, NWH / 128), 256, 0, stream>>>(
            Xb, KPAD, gatWt + (size_t)L * NWH * KPAD, KPAD, WHT, 0,
            nullptr, nullptr, 0, F1, F2, gatA[L], nullptr,
            KPAD / 32, NHID_);
        k_rowstat<<<dim3(NTOT / 4, 4), 256, 0, stream>>>(F1, F2, MASK, RMAX, RDEN);
        // fused PV (XCD-pinned heads)
        k_pv<<<256, 256, 0, stream>>>(WHT, F1, F2, RMAX, RDEN, MASK, Gb);
        // fc + bias + resid
        k_mm<3><<<dim3(NTOT / 128, NPADFC / 128), 256, 0, stream>>>(
            Gb, KPAD, fcWt + (size_t)L * NPADFC * KPAD, KPAD, T, DCOLS,
            fcB[L], xin, DCOLS, nullptr, nullptr, nullptr, nullptr,
            KPAD / 32, DCOLS);
        k_ln<<<NTOT, 256, 0, stream>>>(T, lnG[L], lnB[L], T, (L == 0) ? Xb : nullptr);
        xin = T;
    }
    k_logits<<<NACT, 128, 0, stream>>>(T, logits_W, logits_b, actors_labels, out, LOSSP);
    k_lossfin<<<1, 256, 0, stream>>>(LOSSP, out);
}

// Round 6
// 1396.043 us; speedup vs baseline: 2.9434x; 1.0255x over previous
//
#include <hip/hip_runtime.h>
#include <cstdint>

#define NACT 512
#define NOBJ 3584
#define NTOT 4096
#define DCOLS 1028
#define NHID_ 257
#define OFSZ 2048
#define KPAD 1056          // padded D for bf16 GEMM K
#define NPADH 320          // padded per-head hidden (5 x 64)
#define NWH   1280         // 4 heads x 320 stacked along N
#define NPADFC 1152        // padded fc out cols (18 x 64)

typedef float f32x4 __attribute__((ext_vector_type(4)));
typedef short short8v __attribute__((ext_vector_type(8)));
typedef short short4v __attribute__((ext_vector_type(4)));

// ---- workspace layout (float offsets; all 16B aligned) ----
static const size_t OFF_X0    = 0;                                   // 4096x1028 f32
static const size_t OFF_T     = 4210688;                             // 4096x1028 f32
static const size_t OFF_F1    = 8421376;                             // 4x4096 f32
static const size_t OFF_F2    = 8437760;
static const size_t OFF_RMAX  = 8454144;
static const size_t OFF_RDEN  = 8470528;
static const size_t OFF_LOSSP = 8486912;                             // 512
static const size_t OFF_MASK  = 8487424;                             // 4096x64 u64 = 524288 f
static const size_t OFF_XB    = 9011712;                             // 4096x1056 bf16
static const size_t OFF_GB    = 11174400;                            // 4096x1056 bf16
static const size_t OFF_OFB   = 13337088;                            // 3584x2048 bf16
static const size_t OFF_OBJWT = 17007104;                            // 1024x2048 bf16
static const size_t OFF_GATWT = 18055680;                            // 2 x 1280x1056 bf16
static const size_t OFF_FCWT  = 19407360;                            // 2 x 1152x1056 bf16
static const size_t OFF_WHT   = 20623872;                            // 4 x 320x4096 bf16 (ends 23245312 f)

__device__ __forceinline__ short f2bf(float x) {
    unsigned u = __float_as_uint(x);
    u += 0x7fffu + ((u >> 16) & 1u);
    return (short)(u >> 16);
}
// byte offset inside a [rows][32 bf16] LDS tile, XOR-swizzled 16B chunks.
__device__ __forceinline__ int swz(int row, int chunk) {
    return row * 64 + (((chunk ^ ((row >> 1) & 3))) << 4);
}
// async global->LDS 16B: LDS dest wave-uniform base + lane*16 (linear);
// swizzle achieved by pre-swizzling the per-lane GLOBAL source address.
__device__ __forceinline__ void gload16(const void* g, void* l) {
    __builtin_amdgcn_global_load_lds(
        (const __attribute__((address_space(1))) unsigned int*)g,
        (__attribute__((address_space(3))) unsigned int*)l, 16, 0, 0);
}

// ---------------- geo features (f32 + bf16) ----------------
__global__ void k_geo(const float* __restrict__ ab, const float* __restrict__ ob,
                      float* __restrict__ X, short* __restrict__ Xb) {
    int n = blockIdx.x * blockDim.x + threadIdx.x;
    if (n >= NTOT) return;
    const float* b = (n < NACT) ? &ab[n * 4] : &ob[(n - NACT) * 4];
    float x0 = b[0], y0 = b[1], x1 = b[2], y1 = b[3];
    float g0 = y1 - y0, g1 = x1 - x0;
    float g2 = (x1 - x0) * 0.5f + x0, g3 = (y1 - y0) * 0.5f + y0;
    float* o = &X[(size_t)n * DCOLS + 1024];
    o[0] = g0; o[1] = g1; o[2] = g2; o[3] = g3;
    short* ob2 = &Xb[(size_t)n * KPAD + 1024];
    ob2[0] = f2bf(g0); ob2[1] = f2bf(g1); ob2[2] = f2bf(g2); ob2[3] = f2bf(g3);
}

// ---------------- mean-pool 196 -> 1 (f32 + bf16) ----------------
__global__ __launch_bounds__(256) void k_meanpool(const float* __restrict__ af,
                                                  float* __restrict__ X,
                                                  short* __restrict__ Xb) {
    int w = blockIdx.x * 4 + (threadIdx.x >> 6);
    int lane = threadIdx.x & 63;
    const float* src = af + (size_t)w * 196;
    float s = src[lane] + src[lane + 64] + src[lane + 128];
    if (lane < 4) s += src[192 + lane];
    #pragma unroll
    for (int off = 32; off; off >>= 1) s += __shfl_down(s, off);
    if (lane == 0) {
        int n = w >> 10, c = w & 1023;
        float v = s * (1.0f / 196.0f);
        X[(size_t)n * DCOLS + c] = v;
        Xb[(size_t)n * KPAD + c] = f2bf(v);
    }
}

// ---------------- pack adjacency into bitmask ----------------
__global__ __launch_bounds__(256) void k_packmask(const int* __restrict__ adj,
                                                  unsigned long long* __restrict__ mb) {
    int w = blockIdx.x * 4 + (threadIdx.x >> 6);
    int lane = threadIdx.x & 63;
    int v = adj[(size_t)w * 64 + lane];
    unsigned long long m = __ballot(v > 0);
    if (lane == 0) mb[w] = m;
}

// ---------------- f32 -> bf16 bulk convert (n8 = elems/8) ----------------
__global__ __launch_bounds__(256) void k_convF(const float* __restrict__ src,
                                               short* __restrict__ dst, int n8) {
    int i = blockIdx.x * 256 + threadIdx.x;
    if (i >= n8) return;
    float4 a = *reinterpret_cast<const float4*>(src + (size_t)i * 8);
    float4 b = *reinterpret_cast<const float4*>(src + (size_t)i * 8 + 4);
    short8v o;
    o[0]=f2bf(a.x); o[1]=f2bf(a.y); o[2]=f2bf(a.z); o[3]=f2bf(a.w);
    o[4]=f2bf(b.x); o[5]=f2bf(b.y); o[6]=f2bf(b.z); o[7]=f2bf(b.w);
    *reinterpret_cast<short8v*>(dst + (size_t)i * 8) = o;
}

// ---------------- transpose + convert weights: W[K][N] f32 -> Wt[Npad][Kpad] bf16 ----------------
__global__ __launch_bounds__(256) void k_transpW(const float* __restrict__ W, int K, int N,
                                                 short* __restrict__ Wt, int Kpad) {
    __shared__ float Ws[32][33];
    int k0 = blockIdx.x * 32, n0 = blockIdx.y * 32;
    int t = threadIdx.x;
    #pragma unroll
    for (int i = 0; i < 4; ++i) {
        int j = t + i * 256;
        int r = j >> 5, c = j & 31;
        float v = 0.f;
        if (k0 + r < K && n0 + c < N) v = W[(size_t)(k0 + r) * N + n0 + c];
        Ws[r][c] = v;
    }
    __syncthreads();
    #pragma unroll
    for (int i = 0; i < 4; ++i) {
        int j = t + i * 256;
        int n = j >> 5, k = j & 31;
        Wt[(size_t)(n0 + n) * Kpad + k0 + k] = f2bf(Ws[k][n]);
    }
}

// ---------------- dense bf16 MFMA GEMM, 128x64x32 tile, 4 waves on M, dbuf+gload_lds ----------------
// MODE 0: obj  epi: relu(acc+bias) -> f32 C + bf16 Cbf
// MODE 1: wh   epi: bf16 WHT[h][d][m] + fused f1/f2 atomics (N = 4 heads x 320)
// MODE 3: fc   epi: acc+bias+resid -> f32 C
template <int MODE>
__device__ __forceinline__ void mm_body(
    const short* __restrict__ Ab, int lda,
    const short* __restrict__ Bt, int ldb,
    void* __restrict__ Cptr, int ldc,
    const float* __restrict__ bias,
    const float* __restrict__ resid, int ldr,
    float* __restrict__ F1, float* __restrict__ F2,
    const float* __restrict__ AV,
    short* __restrict__ Cbf,
    int nk, int Nvalid) {
    __shared__ char sm[24576];                 // 2 bufs x (A 128x64B @0 + B 64x64B @8192)
    const int t = threadIdx.x;
    const int m0 = blockIdx.x * 128;
    const int n0 = blockIdx.y * 64;
    const int wv = t >> 6, lane = t & 63, lr = lane & 15, lk = lane >> 4;

    int aoff[2], boff[4];
    #pragma unroll
    for (int i = 0; i < 2; ++i) aoff[i] = swz(32 * wv + 16 * i + lr, lk);
    #pragma unroll
    for (int j = 0; j < 4; ++j) boff[j] = 8192 + swz(16 * j + lr, lk);

    f32x4 acc[2][4];
    #pragma unroll
    for (int i = 0; i < 2; ++i)
        #pragma unroll
        for (int j = 0; j < 4; ++j) acc[i][j] = (f32x4){0.f, 0.f, 0.f, 0.f};

    // stage tile into buf p: wave wv stages A slots {2wv,2wv+1} (its own rows) + B slot wv.
    auto stage = [&](int p, int k0) {
        char* base = sm + p * 12288;
        #pragma unroll
        for (int c = 0; c < 2; ++c) {
            int slot = 2 * wv + c;
            int row = slot * 16 + (lane >> 2);
            int gch = (lane & 3) ^ ((row >> 1) & 3);
            gload16(Ab + (size_t)(m0 + row) * lda + k0 + gch * 8, base + slot * 1024);
        }
        {
            int row = wv * 16 + (lane >> 2);
            int gch = (lane & 3) ^ ((row >> 1) & 3);
            gload16(Bt + (size_t)(n0 + row) * ldb + k0 + gch * 8, base + 8192 + wv * 1024);
        }
    };

    stage(0, 0);
    __syncthreads();
    int p = 0;
    for (int kt = 0; kt < nk; ++kt) {
        if (kt + 1 < nk) stage(p ^ 1, (kt + 1) * 32);
        const char* cb = sm + p * 12288;
        short8v a[2], b[4];
        #pragma unroll
        for (int i = 0; i < 2; ++i) a[i] = *reinterpret_cast<const short8v*>(cb + aoff[i]);
        #pragma unroll
        for (int j = 0; j < 4; ++j) b[j] = *reinterpret_cast<const short8v*>(cb + boff[j]);
        __builtin_amdgcn_s_setprio(1);
        #pragma unroll
        for (int i = 0; i < 2; ++i)
            #pragma unroll
            for (int j = 0; j < 4; ++j)
                acc[i][j] = __builtin_amdgcn_mfma_f32_16x16x32_bf16(a[i], b[j], acc[i][j], 0, 0, 0);
        __builtin_amdgcn_s_setprio(0);
        __syncthreads();                       // drains gloads (vmcnt) + ds reads
        p ^= 1;
    }

    // ---- epilogue ----
    const int mb0 = m0 + 32 * wv + 4 * lk;
    if constexpr (MODE == 0 || MODE == 3) {
        float* Cf = (float*)Cptr;
        #pragma unroll
        for (int i = 0; i < 2; ++i)
            #pragma unroll
            for (int j = 0; j < 4; ++j) {
                int c = n0 + 16 * j + lr;
                if (c < Nvalid) {
                    #pragma unroll
                    for (int rr = 0; rr < 4; ++rr) {
                        int m = mb0 + 16 * i + rr;
                        float v = acc[i][j][rr] + bias[c];
                        if constexpr (MODE == 0) v = fmaxf(v, 0.0f);
                        if constexpr (MODE == 3) v += resid[(size_t)m * ldr + c];
                        Cf[(size_t)m * ldc + c] = v;
                        if constexpr (MODE == 0) Cbf[(size_t)m * KPAD + c] = f2bf(v);
                    }
                }
            }
    } else {  // MODE 1: WHT (d-major within head) + fused f1/f2
        const int h = n0 / NPADH;              // 64 | 320 -> block head-uniform
        const int dwbase = n0 - h * NPADH;
        const float* AVh = AV + h * (2 * NHID_);
        float* F1h = F1 + h * NTOT;
        float* F2h = F2 + h * NTOT;
        short* CwhH = (short*)Cptr + (size_t)h * ((size_t)NPADH * NTOT);
        float la1[4], la2[4];
        #pragma unroll
        for (int j = 0; j < 4; ++j) {
            int d = dwbase + 16 * j + lr;
            la1[j] = (d < NHID_) ? AVh[d] : 0.f;
            la2[j] = (d < NHID_) ? AVh[NHID_ + d] : 0.f;
        }
        #pragma unroll
        for (int i = 0; i < 2; ++i) {
            #pragma unroll
            for (int j = 0; j < 4; ++j) {
                int d = dwbase + 16 * j + lr;
                short4v o;
                o[0] = f2bf(acc[i][j][0]); o[1] = f2bf(acc[i][j][1]);
                o[2] = f2bf(acc[i][j][2]); o[3] = f2bf(acc[i][j][3]);
                *reinterpret_cast<short4v*>(&CwhH[(size_t)d * NTOT + mb0 + 16 * i]) = o;
            }
            #pragma unroll
            for (int rr = 0; rr < 4; ++rr) {
                float s1 = 0.f, s2 = 0.f;
                #pragma unroll
                for (int j = 0; j < 4; ++j) {
                    s1 += acc[i][j][rr] * la1[j];
                    s2 += acc[i][j][rr] * la2[j];
                }
                #pragma unroll
                for (int mk = 1; mk < 16; mk <<= 1) {
                    s1 += __shfl_xor(s1, mk);
                    s2 += __shfl_xor(s2, mk);
                }
                if (lr == 0) {
                    int m = mb0 + 16 * i + rr;
                    atomicAdd(&F1h[m], s1);
                    atomicAdd(&F2h[m], s2);
                }
            }
        }
    }
}

__global__ __launch_bounds__(256, 3) void k_mm_obj(
    const short* Ab, int lda, const short* Bt, int ldb, void* C, int ldc,
    const float* bias, short* Cbf, int nk, int Nvalid) {
    mm_body<0>(Ab, lda, Bt, ldb, C, ldc, bias, nullptr, 0, nullptr, nullptr, nullptr, Cbf, nk, Nvalid);
}
__global__ __launch_bounds__(256, 3) void k_mm_wh(
    const short* Ab, int lda, const short* Bt, int ldb, void* C,
    float* F1, float* F2, const float* AV, int nk) {
    mm_body<1>(Ab, lda, Bt, ldb, C, 0, nullptr, nullptr, 0, F1, F2, AV, nullptr, nk, NHID_);
}
__global__ __launch_bounds__(256, 3) void k_mm_fc(
    const short* Ab, int lda, const short* Bt, int ldb, void* C, int ldc,
    const float* bias, const float* resid, int ldr, int nk, int Nvalid) {
    mm_body<3>(Ab, lda, Bt, ldb, C, ldc, bias, resid, ldr, nullptr, nullptr, nullptr, nullptr, nk, Nvalid);
}

// ---------------- fused PV: 32 rows x full head (320 cols), XCD-pinned heads ----------------
// block b: xcd = b&7, h = xcd>>1 (head -> XCDs {2h,2h+1}); 512 blocks = 2/CU
__global__ __launch_bounds__(256, 2) void k_pv(
    const short* __restrict__ WHT,
    const float* __restrict__ F1, const float* __restrict__ F2,
    const float* __restrict__ RMAX, const float* __restrict__ RDEN,
    const unsigned long long* __restrict__ MB,
    short* __restrict__ Gb) {
    __shared__ char sm[45056];                 // 2 bufs x (Ps 32x64B @0 + Vs 320x64B @2048)
    const int t = threadIdx.x;
    const int i0 = blockIdx.x;                 // 512 blocks
    const int xcd = i0 & 7, kk = i0 >> 3;
    const int h = xcd >> 1;
    const int s = (kk << 1) | (xcd & 1);       // 0..127 per head
    const int m0 = s * 32;
    const short* WhH = WHT + (size_t)h * ((size_t)NPADH * NTOT);
    const float* F2h = F2 + h * NTOT;
    const int gcol = h * NHID_;

    // P-gen: thread -> row pr (32 rows), 4 m-values at octant pq
    const int pr = t >> 3, pq = t & 7;
    const int n = m0 + pr;
    const float f1n = F1[h * NTOT + n];
    const float rmx = RMAX[h * NTOT + n];
    const float psc = 1.0f / RDEN[h * NTOT + n];
    const unsigned long long* mrow = MB + (size_t)n * 64;

    const int wv = t >> 6, lane = t & 63, lr = lane & 15, lk = lane >> 4;
    int aoff[2], boff[5];
    #pragma unroll
    for (int i = 0; i < 2; ++i) aoff[i] = swz(16 * i + lr, lk);
    #pragma unroll
    for (int j = 0; j < 5; ++j) boff[j] = 2048 + swz(80 * wv + 16 * j + lr, lk);

    f32x4 acc[2][5];
    #pragma unroll
    for (int i = 0; i < 2; ++i)
        #pragma unroll
        for (int j = 0; j < 5; ++j) acc[i][j] = (f32x4){0.f, 0.f, 0.f, 0.f};

    auto stageV = [&](int p, int k0) {
        char* vb = sm + p * 22528 + 2048;
        #pragma unroll
        for (int c = 0; c < 5; ++c) {
            int slot2 = 5 * wv + c;
            int row = slot2 * 16 + (lane >> 2);
            int gch = (lane & 3) ^ ((row >> 1) & 3);
            gload16(WhH + (size_t)row * NTOT + k0 + gch * 8, vb + slot2 * 1024);
        }
    };
    auto pgen = [&](int p, int k0) {
        const int mk = k0 + pq * 4;
        unsigned long long wbits = mrow[k0 >> 6] >> ((k0 & 63) + pq * 4);
        float4 q0 = *reinterpret_cast<const float4*>(F2h + mk);
        float fv[4] = {q0.x, q0.y, q0.z, q0.w};
        short4v o;
        #pragma unroll
        for (int j = 0; j < 4; ++j) {
            float e = f1n + fv[j];
            e = e > 0.f ? e : 0.2f * e;
            float pvv = ((wbits >> j) & 1ULL) ? __expf(e - rmx) * psc : 0.f;
            o[j] = f2bf(pvv);
        }
        int off = pr * 64 + ((((pq >> 1) ^ ((pr >> 1) & 3)) << 4) + (pq & 1) * 8);
        *reinterpret_cast<short4v*>(sm + p * 22528 + off) = o;
    };

    stageV(0, 0);
    pgen(0, 0);
    __syncthreads();
    int p = 0;
    for (int kt = 0; kt < NTOT / 32; ++kt) {
        if (kt + 1 < NTOT / 32) {
            stageV(p ^ 1, (kt + 1) * 32);
            pgen(p ^ 1, (kt + 1) * 32);
        }
        const char* cb = sm + p * 22528;
        short8v a[2], b[5];
        #pragma unroll
        for (int i = 0; i < 2; ++i) a[i] = *reinterpret_cast<const short8v*>(cb + aoff[i]);
        #pragma unroll
        for (int j = 0; j < 5; ++j) b[j] = *reinterpret_cast<const short8v*>(cb + boff[j]);
        __builtin_amdgcn_s_setprio(1);
        #pragma unroll
        for (int i = 0; i < 2; ++i)
            #pragma unroll
            for (int j = 0; j < 5; ++j)
                acc[i][j] = __builtin_amdgcn_mfma_f32_16x16x32_bf16(a[i], b[j], acc[i][j], 0, 0, 0);
        __builtin_amdgcn_s_setprio(0);
        __syncthreads();
        p ^= 1;
    }

    // ---- epilogue: elu -> bf16 Gb ----
    #pragma unroll
    for (int j = 0; j < 5; ++j) {
        int d = 80 * wv + 16 * j + lr;
        if (d < NHID_) {
            #pragma unroll
            for (int i = 0; i < 2; ++i)
                #pragma unroll
                for (int rr = 0; rr < 4; ++rr) {
                    int m = m0 + 16 * i + 4 * lk + rr;
                    float v = acc[i][j][rr];
                    v = v > 0.f ? v : expm1f(v);
                    Gb[(size_t)m * KPAD + gcol + d] = f2bf(v);
                }
        }
    }
}

// ---------------- per-row softmax stats (max, denom), online ----------------
__global__ __launch_bounds__(256) void k_rowstat(const float* __restrict__ F1,
                                                 const float* __restrict__ F2,
                                                 const unsigned long long* __restrict__ mb,
                                                 float* __restrict__ RMAX, float* __restrict__ RDEN) {
    __shared__ float f2s[NTOT];
    __shared__ unsigned long long mw[4][64];
    int h = blockIdx.y;
    const float4* src = reinterpret_cast<const float4*>(F2 + (size_t)h * NTOT);
    float4* dst = reinterpret_cast<float4*>(f2s);
    for (int i = threadIdx.x; i < NTOT / 4; i += 256) dst[i] = src[i];
    int wv = threadIdx.x >> 6, lane = threadIdx.x & 63;
    int n = blockIdx.x * 4 + wv;
    mw[wv][lane] = mb[(size_t)n * 64 + lane];
    __syncthreads();
    float f1n = F1[(size_t)h * NTOT + n];
    float rm = -1e30f, rs = 0.f;
    for (int b = 0; b < 64; ++b) {
        unsigned long long wb = mw[wv][b];
        if ((wb >> lane) & 1ULL) {
            float e = f1n + f2s[b * 64 + lane];
            e = e > 0.f ? e : 0.2f * e;
            if (e > rm) { rs *= __expf(rm - e); rm = e; }
            rs += __expf(e - rm);
        }
    }
    #pragma unroll
    for (int off = 32; off; off >>= 1) {
        float m2 = __shfl_down(rm, off), s2 = __shfl_down(rs, off);
        float nm = fmaxf(rm, m2);
        rs = rs * __expf(rm - nm) + s2 * __expf(m2 - nm);
        rm = nm;
    }
    if (lane == 0) {
        if (rs == 0.f) rs = 1.f;
        RMAX[(size_t)h * NTOT + n] = rm;
        RDEN[(size_t)h * NTOT + n] = rs;
    }
}

// ---------------- LayerNorm (in-place safe, optional bf16 out) ----------------
__global__ __launch_bounds__(256) void k_ln(const float* __restrict__ T,
                                            const float* __restrict__ g,
                                            const float* __restrict__ b,
                                            float* __restrict__ O,
                                            short* __restrict__ xb) {
    int n = blockIdx.x;
    const float* row = T + (size_t)n * DCOLS;
    float s = 0.f, q = 0.f;
    for (int i = threadIdx.x; i < DCOLS / 4; i += 256) {
        float4 v = *reinterpret_cast<const float4*>(&row[i * 4]);
        s += v.x + v.y + v.z + v.w;
        q += v.x * v.x + v.y * v.y + v.z * v.z + v.w * v.w;
    }
    __shared__ float ls[2][4];
    int lane = threadIdx.x & 63, wv = threadIdx.x >> 6;
    #pragma unroll
    for (int off = 32; off; off >>= 1) {
        s += __shfl_down(s, off);
        q += __shfl_down(q, off);
    }
    if (lane == 0) { ls[0][wv] = s; ls[1][wv] = q; }
    __syncthreads();
    s = ls[0][0] + ls[0][1] + ls[0][2] + ls[0][3];
    q = ls[1][0] + ls[1][1] + ls[1][2] + ls[1][3];
    float mean = s * (1.0f / DCOLS);
    float var = q * (1.0f / DCOLS) - mean * mean;
    float rstd = rsqrtf(var + 1e-5f);
    float* orow = O + (size_t)n * DCOLS;
    for (int i = threadIdx.x; i < DCOLS; i += 256) {
        float v = (row[i] - mean) * rstd * g[i] + b[i];
        orow[i] = v;
        if (xb) xb[(size_t)n * KPAD + i] = f2bf(v);
    }
}

// ---------------- logits + sigmoid + per-row loss partial ----------------
__global__ __launch_bounds__(128) void k_logits(const float* __restrict__ X,
                                                const float* __restrict__ W,
                                                const float* __restrict__ bias,
                                                const float* __restrict__ Y,
                                                float* __restrict__ out,
                                                float* __restrict__ lossp) {
    __shared__ float xs[DCOLS];
    int n = blockIdx.x;
    for (int i = threadIdx.x; i < DCOLS / 4; i += 128)
        *reinterpret_cast<float4*>(&xs[i * 4]) =
            *reinterpret_cast<const float4*>(&X[(size_t)n * DCOLS + i * 4]);
    __syncthreads();
    float loss = 0.f;
    int c = threadIdx.x;
    if (c < 80) {
        float acc = bias[c];
        for (int k = 0; k < DCOLS; ++k) acc += xs[k] * W[k * 80 + c];
        out[n * 80 + c] = 1.0f / (1.0f + expf(-acc));
        float y = Y[n * 80 + c];
        loss = fmaxf(acc, 0.f) - acc * y + log1pf(expf(-fabsf(acc)));
    }
    __shared__ float lr[2];
    int lane = threadIdx.x & 63, wv = threadIdx.x >> 6;
    #pragma unroll
    for (int off = 32; off; off >>= 1) loss += __shfl_down(loss, off);
    if (lane == 0) lr[wv] = loss;
    __syncthreads();
    if (threadIdx.x == 0) lossp[n] = lr[0] + lr[1];
}

__global__ __launch_bounds__(256) void k_lossfin(const float* __restrict__ lossp,
                                                 float* __restrict__ out) {
    float s = 0.f;
    for (int i = threadIdx.x; i < NACT; i += 256) s += lossp[i];
    #pragma unroll
    for (int off = 32; off; off >>= 1) s += __shfl_down(s, off);
    __shared__ float lr[4];
    int lane = threadIdx.x & 63, wv = threadIdx.x >> 6;
    if (lane == 0) lr[wv] = s;
    __syncthreads();
    if (threadIdx.x == 0) out[NACT * 80] = (lr[0] + lr[1] + lr[2] + lr[3]) / (float)(NACT * 80);
}

// ---------------- host launcher ----------------
extern "C" void kernel_launch(void* const* d_in, const int* in_sizes, int n_in,
                              void* d_out, int out_size, void* d_ws, size_t ws_size,
                              hipStream_t stream) {
    const float* actors_features  = (const float*)d_in[0];
    const float* actors_labels    = (const float*)d_in[1];
    const float* actors_boxes     = (const float*)d_in[2];
    const float* objects_features = (const float*)d_in[3];
    const float* objects_boxes    = (const float*)d_in[4];
    const int*   adj              = (const int*)d_in[5];
    const float* obj_W    = (const float*)d_in[6];
    const float* obj_b    = (const float*)d_in[7];
    const float* gatW[2]  = {(const float*)d_in[8],  (const float*)d_in[14]};
    const float* gatA[2]  = {(const float*)d_in[9],  (const float*)d_in[15]};
    const float* fcW[2]   = {(const float*)d_in[10], (const float*)d_in[16]};
    const float* fcB[2]   = {(const float*)d_in[11], (const float*)d_in[17]};
    const float* lnG[2]   = {(const float*)d_in[12], (const float*)d_in[18]};
    const float* lnB[2]   = {(const float*)d_in[13], (const float*)d_in[19]};
    const float* logits_W = (const float*)d_in[20];
    const float* logits_b = (const float*)d_in[21];
    float* out = (float*)d_out;

    float* ws   = (float*)d_ws;
    float* X0   = ws + OFF_X0;
    float* T    = ws + OFF_T;
    float* F1   = ws + OFF_F1;
    float* F2   = ws + OFF_F2;
    float* RMAX = ws + OFF_RMAX;
    float* RDEN = ws + OFF_RDEN;
    float* LOSSP= ws + OFF_LOSSP;
    unsigned long long* MASK = (unsigned long long*)(ws + OFF_MASK);
    short* Xb    = (short*)(ws + OFF_XB);
    short* Gb    = (short*)(ws + OFF_GB);
    short* OFb   = (short*)(ws + OFF_OFB);
    short* objWt = (short*)(ws + OFF_OBJWT);
    short* gatWt = (short*)(ws + OFF_GATWT);
    short* fcWt  = (short*)(ws + OFF_FCWT);
    short* WHT   = (short*)(ws + OFF_WHT);

    hipMemsetAsync(F1, 0, 2 * 4 * NTOT * sizeof(float), stream);           // F1+F2
    hipMemsetAsync(Gb, 0, (size_t)NTOT * KPAD * 2, stream);                // pad cols must be 0
    hipMemsetAsync(Xb, 0, (size_t)NTOT * KPAD * 2, stream);                // pad cols must be 0

    k_geo<<<(NTOT + 255) / 256, 256, 0, stream>>>(actors_boxes, objects_boxes, X0, Xb);
    k_meanpool<<<(NACT * 1024) / 4, 256, 0, stream>>>(actors_features, X0, Xb);
    k_packmask<<<(NTOT * 64) / 4, 256, 0, stream>>>(adj, MASK);
    k_convF<<<(NOBJ * OFSZ / 8 + 255) / 256, 256, 0, stream>>>(objects_features, OFb, NOBJ * OFSZ / 8);

    // weight transposes (bf16, padded)
    k_transpW<<<dim3(64, 32), 256, 0, stream>>>(obj_W, OFSZ, 1024, objWt, OFSZ);
    for (int L = 0; L < 2; ++L) {
        for (int h = 0; h < 4; ++h)
            k_transpW<<<dim3(33, 10), 256, 0, stream>>>(
                gatW[L] + (size_t)h * DCOLS * NHID_, DCOLS, NHID_,
                gatWt + (size_t)L * NWH * KPAD + (size_t)h * NPADH * KPAD, KPAD);
        k_transpW<<<dim3(33, 36), 256, 0, stream>>>(
            fcW[L], DCOLS, DCOLS, fcWt + (size_t)L * NPADFC * KPAD, KPAD);
    }

    // objects reducer: relu(of @ obj_W + b) -> X0 rows [512,4096) + Xb bf16
    k_mm_obj<<<dim3(NOBJ / 128, 1024 / 64), 256, 0, stream>>>(
        OFb, OFSZ, objWt, OFSZ, X0 + (size_t)NACT * DCOLS, DCOLS,
        obj_b, Xb + (size_t)NACT * KPAD, OFSZ / 32, 1024);

    const float* xin = X0;
    for (int L = 0; L < 2; ++L) {
        if (L == 1)
            hipMemsetAsync(F1, 0, 2 * 4 * NTOT * sizeof(float), stream);
        // Wh GEMM (all heads, N=1280) + fused f1/f2
        k_mm_wh<<<dim3(NTOT / 128, NWH / 64), 256, 0, stream>>>(
            Xb, KPAD, gatWt + (size_t)L * NWH * KPAD, KPAD, WHT, F1, F2, gatA[L], KPAD / 32);
        k_rowstat<<<dim3(NTOT / 4, 4), 256, 0, stream>>>(F1, F2, MASK, RMAX, RDEN);
        // fused PV (XCD-pinned heads, 512 blocks)
        k_pv<<<512, 256, 0, stream>>>(WHT, F1, F2, RMAX, RDEN, MASK, Gb);
        // fc + bias + resid
        k_mm_fc<<<dim3(NTOT / 128, NPADFC / 64), 256, 0, stream>>>(
            Gb, KPAD, fcWt + (size_t)L * NPADFC * KPAD, KPAD, T, DCOLS,
            fcB[L], xin, DCOLS, KPAD / 32, DCOLS);
        k_ln<<<NTOT, 256, 0, stream>>>(T, lnG[L], lnB[L], T, (L == 0) ? Xb : nullptr);
        xin = T;
    }
    k_logits<<<NACT, 128, 0, stream>>>(T, logits_W, logits_b, actors_labels, out, LOSSP);
    k_lossfin<<<1, 256, 0, stream>>>(LOSSP, out);
}